// Round 12
// baseline (302.895 us; speedup 1.0000x reference)
//
#include <hip/hip_runtime.h>

#define D 1024
#define NB1 48
#define NB2 48
#define RR 36
#define LL 30
#define NH 4

typedef short bf16x8 __attribute__((ext_vector_type(8)));
typedef float f32x4 __attribute__((ext_vector_type(4)));
typedef float f32x2 __attribute__((ext_vector_type(2)));
typedef unsigned short u16x8 __attribute__((ext_vector_type(8)));

#define MFMA16(a, b, c) __builtin_amdgcn_mfma_f32_16x16x32_bf16(a, b, c, 0, 0, 0)

__device__ __forceinline__ unsigned short f2bf(float x) {
  unsigned u = __float_as_uint(x);
  u += 0x7FFF + ((u >> 16) & 1);
  return (unsigned short)(u >> 16);
}
__device__ __forceinline__ float bf2f(unsigned short h) {
  return __uint_as_float(((unsigned)h) << 16);
}
__device__ __forceinline__ void split8(const float* v, bf16x8& h8, bf16x8& l8) {
  u16x8 hi, lo;
#pragma unroll
  for (int i = 0; i < 8; ++i) {
    unsigned short h = f2bf(v[i]);
    hi[i] = h;
    lo[i] = f2bf(v[i] - bf2f(h));
  }
  h8 = __builtin_bit_cast(bf16x8, hi);
  l8 = __builtin_bit_cast(bf16x8, lo);
}
__device__ __forceinline__ f32x2 shflx2(f32x2 v, int m) {
  double d = __builtin_bit_cast(double, v);
  d = __shfl_xor(d, m);
  return __builtin_bit_cast(f32x2, d);
}

// ---- fp32 row-major (rows x 1024) -> split-bf16 MFMA fragment layout ----
__device__ __forceinline__ void conv_body(const float* __restrict__ X,
                                          unsigned short* __restrict__ out,
                                          int rows, int g) {
  const int lane = threadIdx.x & 63;
  const int tile = g >> 5, kc = g & 31;
  const int row = tile * 16 + (lane & 15);
  const int k = kc * 32 + (lane >> 4) * 8;
  float v[8];
  if (row < rows) {
    const float4* s = (const float4*)(X + (size_t)row * 1024 + k);
    float4 x0 = s[0], x1 = s[1];
    v[0] = x0.x; v[1] = x0.y; v[2] = x0.z; v[3] = x0.w;
    v[4] = x1.x; v[5] = x1.y; v[6] = x1.z; v[7] = x1.w;
  } else {
#pragma unroll
    for (int i = 0; i < 8; ++i) v[i] = 0.f;
  }
  bf16x8 hi, lo;
  split8(v, hi, lo);
  bf16x8* o = (bf16x8*)(out + (size_t)g * 1024 + lane * 8);
  o[0] = hi;
  o[64] = lo;
}

// 6 input matrices in one launch + w2 transpose (y==0, x<4). grid (864, 6)
__global__ __launch_bounds__(256) void conv6(
    const float* __restrict__ v1, const float* __restrict__ v2,
    const float* __restrict__ wimg, const float* __restrict__ wtxt,
    const float* __restrict__ w1a, const float* __restrict__ w1b,
    const float* __restrict__ w2a, const float* __restrict__ w2b,
    unsigned short* v1f, unsigned short* v2f, unsigned short* wimgf,
    unsigned short* wtxtf, unsigned short* w1af, unsigned short* w1bf,
    float4* __restrict__ w2at, float4* __restrict__ w2bt) {
  if (blockIdx.y == 0 && blockIdx.x < 4) {
    int col = blockIdx.x * 256 + threadIdx.x;
    w2at[col] = make_float4(w2a[col], w2a[1024 + col], w2a[2048 + col], w2a[3072 + col]);
    w2bt[col] = make_float4(w2b[col], w2b[1024 + col], w2b[2048 + col], w2b[3072 + col]);
  }
  const float* X; unsigned short* O; int rows;
  switch (blockIdx.y) {
    case 0: X = v1; O = v1f; rows = 1728; break;
    case 1: X = v2; O = v2f; rows = 1440; break;
    case 2: X = wimg; O = wimgf; rows = 1024; break;
    case 3: X = wtxt; O = wtxtf; rows = 1024; break;
    case 4: X = w1a; O = w1af; rows = 1024; break;
    default: X = w1b; O = w1bf; rows = 1024; break;
  }
  const int tiles = (rows + 15) >> 4;
  const int g = blockIdx.x * 4 + (threadIdx.x >> 6);
  if (g >= tiles * 32) return;
  conv_body(X, O, rows, g);
}

// G2a -> B-frag [b][nt(64)][part(2)][512] ; G1b -> [a][nt(64)][kc(2)][part(2)][512]
// grid (768, 2)
__global__ __launch_bounds__(256) void convG(const float* __restrict__ G2a,
                                             const float* __restrict__ G1b,
                                             unsigned short* G2aF,
                                             unsigned short* G1bF) {
  const int t = threadIdx.x, lane = t & 63;
  const int bb = blockIdx.x >> 4;
  const int nt = ((blockIdx.x & 15) << 2) + (t >> 6);
  const int c = lane & 15, q = lane >> 4;
  if (blockIdx.y == 0) {
    float v[8];
#pragma unroll
    for (int j = 0; j < 8; ++j) {
      int l = q * 8 + j;
      v[j] = (l < LL) ? G2a[(size_t)(bb * LL + l) * D + nt * 16 + c] : 0.f;
    }
    bf16x8 hi, lo;
    split8(v, hi, lo);
    bf16x8* o = (bf16x8*)(G2aF + ((size_t)(bb * 64 + nt) * 2) * 512 + lane * 8);
    o[0] = hi;
    o[64] = lo;
  } else {
#pragma unroll
    for (int kc = 0; kc < 2; ++kc) {
      float v[8];
#pragma unroll
      for (int j = 0; j < 8; ++j) {
        int r = kc * 32 + q * 8 + j;
        v[j] = (r < RR) ? G1b[(size_t)(bb * RR + r) * D + nt * 16 + c] : 0.f;
      }
      bf16x8 hi, lo;
      split8(v, hi, lo);
      bf16x8* o = (bf16x8*)(G1bF + (((size_t)(bb * 64 + nt) * 2 + kc) * 2) * 512 + lane * 8);
      o[0] = hi;
      o[64] = lo;
    }
  }
}

// ---- split-bf16 MFMA GEMM core: 2 waves/block, each 4x4 tiles (128x64 out) ----
#define LOAD_FRAGS(AH, AL, BH, BL)                                              \
  {                                                                             \
    _Pragma("unroll") for (int i = 0; i < 4; ++i) {                             \
      AH[i] = Af[ab[i]]; AL[i] = Af[ab[i] + 64]; ab[i] += 128;                  \
    }                                                                           \
    _Pragma("unroll") for (int j = 0; j < 4; ++j) {                             \
      BH[j] = Bf[bb[j]]; BL[j] = Bf[bb[j] + 64]; bb[j] += 128;                  \
    }                                                                           \
  }

#define MFMA_SET(AH, AL, BH, BL)                                                \
  _Pragma("unroll") for (int i = 0; i < 4; ++i)                                 \
      _Pragma("unroll") for (int j = 0; j < 4; ++j) {                           \
    acc[i][j] = MFMA16(AH[i], BH[j], acc[i][j]);                                \
    acc[i][j] = MFMA16(AL[i], BH[j], acc[i][j]);                                \
    acc[i][j] = MFMA16(AH[i], BL[j], acc[i][j]);                                \
  }

__device__ __forceinline__ void gemm2w_acc(const bf16x8* __restrict__ Af,
                                           const bf16x8* __restrict__ Bf,
                                           int Mtiles, int Ntiles,
                                           int mb, int nb, int lane,
                                           f32x4 (&acc)[4][4]) {
  int ab[4], bb[4];
#pragma unroll
  for (int i = 0; i < 4; ++i) {
    int tm = mb + i; if (tm > Mtiles - 1) tm = Mtiles - 1;
    ab[i] = tm * 4096 + lane;
    int tn = nb + i; if (tn > Ntiles - 1) tn = Ntiles - 1;
    bb[i] = tn * 4096 + lane;
  }
#pragma unroll
  for (int i = 0; i < 4; ++i)
#pragma unroll
    for (int j = 0; j < 4; ++j) acc[i][j] = (f32x4){0.f, 0.f, 0.f, 0.f};

  bf16x8 ahA[4], alA[4], bhA[4], blA[4];
  bf16x8 ahB[4], alB[4], bhB[4], blB[4];
  LOAD_FRAGS(ahA, alA, bhA, blA);
#pragma unroll 1
  for (int kc = 0; kc < 30; kc += 2) {
    LOAD_FRAGS(ahB, alB, bhB, blB);
    MFMA_SET(ahA, alA, bhA, blA);
    LOAD_FRAGS(ahA, alA, bhA, blA);
    MFMA_SET(ahB, alB, bhB, blB);
  }
  LOAD_FRAGS(ahB, alB, bhB, blB);
  MFMA_SET(ahA, alA, bhA, blA);
  MFMA_SET(ahB, alB, bhB, blB);
}

__device__ __forceinline__ void gemm2w_store_fp32(f32x4 (&acc)[4][4],
                                                  float* __restrict__ C,
                                                  int M, int N, float scale,
                                                  int mb, int nb, int lane) {
  const int c16 = lane & 15, q = lane >> 4;
#pragma unroll
  for (int i = 0; i < 4; ++i) {
#pragma unroll
    for (int reg = 0; reg < 4; ++reg) {
      int r = (mb + i) * 16 + q * 4 + reg;
      if (r < M) {
#pragma unroll
        for (int j = 0; j < 4; ++j) {
          int col = (nb + j) * 16 + c16;
          if (col < N) C[(size_t)r * N + col] = acc[i][j][reg] * scale;
        }
      }
    }
  }
}

// k projections only (cross_s's sole dependency). grid (16, 14, 2) x 128.
// Outputs split-bf16 k-fragments DIRECTLY via LDS transpose epilogue.
__global__ __launch_bounds__(128) void projK(
    const bf16x8* __restrict__ v1f, const bf16x8* __restrict__ v2f,
    const bf16x8* __restrict__ wimgf, const bf16x8* __restrict__ wtxtf,
    unsigned short* k1f, unsigned short* k2f) {
  const int z = blockIdx.z;
  const int lane = threadIdx.x & 63;
  const int w = threadIdx.x >> 6;
  const int mb = blockIdx.y * 8 + w * 4;
  const int nb = blockIdx.x * 4;
  const bf16x8* Af = (z == 0) ? v1f : v2f;
  const bf16x8* Bf = (z == 0) ? wimgf : wtxtf;
  const int Mt = (z == 0) ? 108 : 90;
  if ((int)blockIdx.y * 8 >= Mt) return;

  __shared__ __align__(16) float tlds[2][4][16][68];

  f32x4 acc[4][4];
  gemm2w_acc(Af, Bf, Mt, 64, mb, nb, lane, acc);

  unsigned short* F = z ? k2f : k1f;
  const int c16 = lane & 15, q = lane >> 4;
#pragma unroll
  for (int i = 0; i < 4; ++i)
#pragma unroll
    for (int j = 0; j < 4; ++j)
#pragma unroll
      for (int reg = 0; reg < 4; ++reg)
        tlds[w][i][q * 4 + reg][j * 16 + c16] = acc[i][j][reg];
  __builtin_amdgcn_sched_barrier(0);
  const int r16 = lane & 15, q2 = lane >> 4;
#pragma unroll
  for (int i = 0; i < 4; ++i) {
    if (mb + i < Mt) {
#pragma unroll
      for (int kcl = 0; kcl < 2; ++kcl) {
        const float* rp = &tlds[w][i][r16][kcl * 32 + q2 * 8];
        float4 x0 = *(const float4*)rp;
        float4 x1 = *(const float4*)(rp + 4);
        float v[8];
        v[0] = x0.x; v[1] = x0.y; v[2] = x0.z; v[3] = x0.w;
        v[4] = x1.x; v[5] = x1.y; v[6] = x1.z; v[7] = x1.w;
        bf16x8 hi, lo;
        split8(v, hi, lo);
        size_t g = (size_t)(mb + i) * 32 + (nb >> 1) + kcl;
        bf16x8* o = (bf16x8*)(F + g * 1024 + lane * 8);
        o[0] = hi;
        o[64] = lo;
      }
    }
  }
}

// G projections + cross GEMM co-scheduled in ONE launch (cross is grid-starved
// at 324 blocks = 1.27/CU; projG fills the idle CUs). grid (27, 14, 3) x 128.
// z0: G2a = v2f*w1af (fp32). z1: G1b = v1f*w1bf (fp32). z2: S = k2*k1^T.
__global__ __launch_bounds__(128) void projG_cross(
    const bf16x8* __restrict__ v1f, const bf16x8* __restrict__ v2f,
    const bf16x8* __restrict__ w1af, const bf16x8* __restrict__ w1bf,
    const bf16x8* __restrict__ k2f, const bf16x8* __restrict__ k1f,
    float* G2a, float* G1b, float* Sbuf) {
  const int z = blockIdx.z;
  const int lane = threadIdx.x & 63;
  const int w = threadIdx.x >> 6;
  f32x4 acc[4][4];
  if (z == 2) {
    if (blockIdx.x >= 27 || blockIdx.y >= 12) return;
    const int mb = blockIdx.y * 8 + w * 4;
    const int nb = blockIdx.x * 4;
    gemm2w_acc(k2f, k1f, 90, 108, mb, nb, lane, acc);
    gemm2w_store_fp32(acc, Sbuf, 1440, 1728, 0.03125f, mb, nb, lane);
    return;
  }
  if (blockIdx.x >= 16) return;
  const bf16x8* Af = (z == 0) ? v2f : v1f;
  const bf16x8* Bf = (z == 0) ? w1af : w1bf;
  float* C = (z == 0) ? G2a : G1b;
  const int Mt = (z == 0) ? 90 : 108;
  const int M = (z == 0) ? 1440 : 1728;
  if ((int)blockIdx.y * 8 >= Mt) return;
  const int mb = blockIdx.y * 8 + w * 4;
  const int nb = blockIdx.x * 4;
  gemm2w_acc(Af, Bf, Mt, 64, mb, nb, lane, acc);
  gemm2w_store_fp32(acc, C, M, 1024, 1.f, mb, nb, lane);
}

// -------- wave-per-(pair,dir) kernel: grid 1152 x 256; zero __syncthreads ----
// Block composition: all 4 waves SAME dir + SAME B-matrix; XCD pinning via bx%8
// (R8-verified: FETCH 85->23MB). LDS 24KB (R11-verified): clamped A-rows,
// register-built K-pad.
__global__ __launch_bounds__(256, 4) void pair_dir(
    const float* __restrict__ Sb,
    const bf16x8* __restrict__ G2aF, const bf16x8* __restrict__ G1bF,
    const float* __restrict__ b1a, const float4* __restrict__ w2at, const float* __restrict__ b2a,
    const float* __restrict__ b1b, const float4* __restrict__ w2bt, const float* __restrict__ b2b,
    float* __restrict__ U1buf, float* __restrict__ U2buf) {
  const int t = threadIdx.x, lane = t & 63, w = t >> 6;
  const int bx = blockIdx.x;
  int a, b, dir;
  if (bx < 576) {
    dir = 0;
    const int lo = bx & 7, i = bx >> 3;
    b = lo + 8 * (i % 6);
    a = (i / 6) * 4 + w;
  } else {
    dir = 1;
    const int bx2 = bx - 576;
    const int lo = bx2 & 7, i = bx2 >> 3;
    a = lo + 8 * (i % 6);
    b = (i / 6) * 4 + w;
  }
  const int c16 = lane & 15, q = lane >> 4;

  union WSM {
    struct { float p2s[36][36]; float sa[36][NH]; float qa[36]; } A;   // 5904 B
    struct { float p1s[30][36]; float sbm[30][NH]; float qb[30]; } B;  // 4920 B
  };
  __shared__ __align__(16) WSM sm[4];
  WSM& S = sm[w];

  const float* Sab = Sb + (size_t)(b * LL) * 1728 + a * RR;

  if (dir == 0) {
    // ================= direction A (one wave) =================
    if (lane < RR) { S.A.p2s[lane][30] = 0.f; S.A.p2s[lane][31] = 0.f; }
    __builtin_amdgcn_sched_barrier(0);
    for (int i = lane; i < LL * RR; i += 64) {
      int l = i / RR, r = i - l * RR;
      S.A.p2s[r][l] = Sab[(size_t)l * 1728 + r];
    }
    __builtin_amdgcn_sched_barrier(0);
    if (lane < RR) {
      const int r = lane;
      float m = -1e30f;
      for (int l = 0; l < LL; ++l) m = fmaxf(m, S.A.p2s[r][l]);
      float s = 0.f;
      for (int l = 0; l < LL; ++l) {
        float e = __expf(S.A.p2s[r][l] - m);
        S.A.p2s[r][l] = e;
        s += e;
      }
      float inv = 1.f / s;
      for (int l = 0; l < LL; ++l) S.A.p2s[r][l] *= inv;
    }
    __builtin_amdgcn_sched_barrier(0);

    bf16x8 pAh[3], pAl[3];
#pragma unroll
    for (int mt = 0; mt < 3; ++mt) {
      int rr = mt * 16 + c16;
      if (rr > RR - 1) rr = RR - 1;      // clamped: feeds discarded score rows
      float v[8];
      const float* rp = &S.A.p2s[rr][q * 8];
      float4 x0 = *(const float4*)rp;
      float4 x1 = *(const float4*)(rp + 4);
      v[0] = x0.x; v[1] = x0.y; v[2] = x0.z; v[3] = x0.w;
      v[4] = x1.x; v[5] = x1.y; v[6] = x1.z; v[7] = x1.w;
      split8(v, pAh[mt], pAl[mt]);
    }

    f32x2 sc01[3][4], sc23[3][4];
#pragma unroll
    for (int mt = 0; mt < 3; ++mt)
#pragma unroll
      for (int reg = 0; reg < 4; ++reg) {
        sc01[mt][reg] = (f32x2){0.f, 0.f};
        sc23[mt][reg] = (f32x2){0.f, 0.f};
      }

    const bf16x8* gA = G2aF + (size_t)(b * 64) * 128 + lane;
#pragma unroll 2
    for (int it = 0; it < 64; ++it) {
      const bf16x8* gp = gA + (size_t)it * 128;
      bf16x8 Bh = gp[0], Bl = gp[64];
      const int col = it * 16 + c16;
      float4 wv = w2at[col];
      float bias = b1a[col];
      f32x2 w01 = {wv.x, wv.y}, w23 = {wv.z, wv.w};
#pragma unroll
      for (int mt = 0; mt < 3; ++mt) {
        f32x4 acc = {bias, bias, bias, bias};
        __builtin_amdgcn_s_setprio(1);
        acc = MFMA16(pAh[mt], Bh, acc);
        acc = MFMA16(pAl[mt], Bh, acc);
        acc = MFMA16(pAh[mt], Bl, acc);
        __builtin_amdgcn_s_setprio(0);
#pragma unroll
        for (int reg = 0; reg < 4; ++reg) {
          float hv = fmaxf(acc[reg], 0.f);
          f32x2 hv2 = {hv, hv};
          sc01[mt][reg] += hv2 * w01;
          sc23[mt][reg] += hv2 * w23;
        }
      }
    }
    f32x2 b01 = {b2a[0], b2a[1]}, b23 = {b2a[2], b2a[3]};
#pragma unroll
    for (int mt = 0; mt < 3; ++mt)
#pragma unroll
      for (int reg = 0; reg < 4; ++reg) {
        f32x2 v01 = sc01[mt][reg], v23 = sc23[mt][reg];
#pragma unroll
        for (int m = 1; m <= 8; m <<= 1) {
          v01 += shflx2(v01, m);
          v23 += shflx2(v23, m);
        }
        int row = mt * 16 + q * 4 + reg;
        if (c16 == 0 && row < RR) {
          f32x2* rp = (f32x2*)&S.A.sa[row][0];
          rp[0] = v01 + b01;
          rp[1] = v23 + b23;
        }
      }
    __builtin_amdgcn_sched_barrier(0);
    // head softmax over 36 rows, 16 lanes/head; then qa via cross-head shuffles
    {
      const int h = q, i = c16;
      float x0 = S.A.sa[i][h];
      float x1 = S.A.sa[i + 16][h];
      float x2 = (i < 4) ? S.A.sa[i + 32][h] : -1e30f;
      float m = fmaxf(fmaxf(x0, x1), x2);
      m = fmaxf(m, __shfl_xor(m, 1));
      m = fmaxf(m, __shfl_xor(m, 2));
      m = fmaxf(m, __shfl_xor(m, 4));
      m = fmaxf(m, __shfl_xor(m, 8));
      float e0 = __expf(x0 - m), e1 = __expf(x1 - m);
      float e2 = (i < 4) ? __expf(x2 - m) : 0.f;
      float s = e0 + e1 + e2;
      s += __shfl_xor(s, 1);
      s += __shfl_xor(s, 2);
      s += __shfl_xor(s, 4);
      s += __shfl_xor(s, 8);
      float inv = 0.25f / s;
      float p0 = e0 * inv, p1 = e1 * inv, p2v = e2 * inv;
      p0 += __shfl_xor(p0, 16); p0 += __shfl_xor(p0, 32);
      p1 += __shfl_xor(p1, 16); p1 += __shfl_xor(p1, 32);
      p2v += __shfl_xor(p2v, 16); p2v += __shfl_xor(p2v, 32);
      if (q == 0) {
        S.A.qa[i] = p0;
        S.A.qa[i + 16] = p1;
        if (i < 4) S.A.qa[i + 32] = p2v;
      }
    }
    __builtin_amdgcn_sched_barrier(0);
    // u2[l] = sum_r qa[r] * p2[r][l]
    if (lane < LL) {
      const int l = lane;
      float x = 0.f;
      for (int r = 0; r < RR; ++r) x = fmaf(S.A.qa[r], S.A.p2s[r][l], x);
      U2buf[((size_t)b * 48 + a) * 32 + l] = x;
    }
  } else {
    // ================= direction B (one wave) =================
    for (int i = lane; i < LL * RR; i += 64) {
      int l = i / RR, r = i - l * RR;
      S.B.p1s[l][r] = Sab[(size_t)l * 1728 + r];
    }
    __builtin_amdgcn_sched_barrier(0);
    if (lane < LL) {
      const int l = lane;
      float m = -1e30f;
      for (int r = 0; r < RR; ++r) m = fmaxf(m, S.B.p1s[l][r]);
      float s = 0.f;
      for (int r = 0; r < RR; ++r) {
        float e = __expf(S.B.p1s[l][r] - m);
        S.B.p1s[l][r] = e;
        s += e;
      }
      float inv = 1.f / s;
      for (int r = 0; r < RR; ++r) S.B.p1s[l][r] *= inv;
    }
    __builtin_amdgcn_sched_barrier(0);

    bf16x8 pBh[2][2], pBl[2][2];
#pragma unroll
    for (int mt = 0; mt < 2; ++mt) {
      int rr = mt * 16 + c16;
      if (rr > LL - 1) rr = LL - 1;      // clamped: feeds discarded score rows
      {
        float v[8];
        const float* rp = &S.B.p1s[rr][q * 8];
        float4 x0 = *(const float4*)rp;
        float4 x1 = *(const float4*)(rp + 4);
        v[0] = x0.x; v[1] = x0.y; v[2] = x0.z; v[3] = x0.w;
        v[4] = x1.x; v[5] = x1.y; v[6] = x1.z; v[7] = x1.w;
        split8(v, pBh[mt][0], pBl[mt][0]);
      }
      {
        float v[8];
#pragma unroll
        for (int j = 0; j < 8; ++j) {
          int r = 32 + q * 8 + j;
          v[j] = (r < RR) ? S.B.p1s[rr][r] : 0.f;
        }
        split8(v, pBh[mt][1], pBl[mt][1]);
      }
    }

    f32x2 sc01[2][4], sc23[2][4];
#pragma unroll
    for (int mt = 0; mt < 2; ++mt)
#pragma unroll
      for (int reg = 0; reg < 4; ++reg) {
        sc01[mt][reg] = (f32x2){0.f, 0.f};
        sc23[mt][reg] = (f32x2){0.f, 0.f};
      }

    const bf16x8* gB = G1bF + (size_t)(a * 64) * 256 + lane;
#pragma unroll 2
    for (int it = 0; it < 64; ++it) {
      const bf16x8* gp = gB + (size_t)it * 256;
      bf16x8 B0h = gp[0], B0l = gp[64], B1h = gp[128], B1l = gp[192];
      const int col = it * 16 + c16;
      float4 wv = w2bt[col];
      float bias = b1b[col];
      f32x2 w01 = {wv.x, wv.y}, w23 = {wv.z, wv.w};
#pragma unroll
      for (int mt = 0; mt < 2; ++mt) {
        f32x4 acc = {bias, bias, bias, bias};
        __builtin_amdgcn_s_setprio(1);
        acc = MFMA16(pBh[mt][0], B0h, acc);
        acc = MFMA16(pBl[mt][0], B0h, acc);
        acc = MFMA16(pBh[mt][0], B0l, acc);
        acc = MFMA16(pBh[mt][1], B1h, acc);
        acc = MFMA16(pBl[mt][1], B1h, acc);
        acc = MFMA16(pBh[mt][1], B1l, acc);
        __builtin_amdgcn_s_setprio(0);
#pragma unroll
        for (int reg = 0; reg < 4; ++reg) {
          float hv = fmaxf(acc[reg], 0.f);
          f32x2 hv2 = {hv, hv};
          sc01[mt][reg] += hv2 * w01;
          sc23[mt][reg] += hv2 * w23;
        }
      }
    }
    f32x2 b01 = {b2b[0], b2b[1]}, b23 = {b2b[2], b2b[3]};
#pragma unroll
    for (int mt = 0; mt < 2; ++mt)
#pragma unroll
      for (int reg = 0; reg < 4; ++reg) {
        f32x2 v01 = sc01[mt][reg], v23 = sc23[mt][reg];
#pragma unroll
        for (int m = 1; m <= 8; m <<= 1) {
          v01 += shflx2(v01, m);
          v23 += shflx2(v23, m);
        }
        int row = mt * 16 + q * 4 + reg;
        if (c16 == 0 && row < LL) {
          f32x2* rp = (f32x2*)&S.B.sbm[row][0];
          rp[0] = v01 + b01;
          rp[1] = v23 + b23;
        }
      }
    __builtin_amdgcn_sched_barrier(0);
    // head softmax over 30 rows; qb via cross-head shuffles
    {
      const int h = q, i = c16;
      float x0 = S.B.sbm[i][h];
      float x1 = (i < 14) ? S.B.sbm[i + 16][h] : -1e30f;
      float m = fmaxf(x0, x1);
      m = fmaxf(m, __shfl_xor(m, 1));
      m = fmaxf(m, __shfl_xor(m, 2));
      m = fmaxf(m, __shfl_xor(m, 4));
      m = fmaxf(m, __shfl_xor(m, 8));
      float e0 = __expf(x0 - m);
      float e1 = (i < 14) ? __expf(x1 - m) : 0.f;
      float s = e0 + e1;
      s += __shfl_xor(s, 1);
      s += __shfl_xor(s, 2);
      s += __shfl_xor(s, 4);
      s += __shfl_xor(s, 8);
      float inv = 0.25f / s;
      float p0 = e0 * inv, p1 = e1 * inv;
      p0 += __shfl_xor(p0, 16); p0 += __shfl_xor(p0, 32);
      p1 += __shfl_xor(p1, 16); p1 += __shfl_xor(p1, 32);
      if (q == 0) {
        S.B.qb[i] = p0;
        if (i < 14) S.B.qb[i + 16] = p1;
      }
    }
    __builtin_amdgcn_sched_barrier(0);
    // u1[r] = sum_l qb[l] * p1[l][r]
    if (lane < RR) {
      const int r = lane;
      float x = 0.f;
      for (int l = 0; l < LL; ++l) x = fmaf(S.B.qb[l], S.B.p1s[l][r], x);
      U1buf[((size_t)a * 48 + b) * 40 + r] = x;
    }
  }
}

// Y_A[b] = U2_b(48x30) * V2_b(30x1024) ; Y_B[a] = U1_a(48x36) * V1_a(36x1024)
// grid (48, 2, 4) x 256. Each thread owns one col, 48 accumulators.
__global__ __launch_bounds__(256) void y_batch(
    const float* __restrict__ v1, const float* __restrict__ v2,
    const float* __restrict__ U1buf, const float* __restrict__ U2buf,
    float* __restrict__ YA, float* __restrict__ YB) {
  const int bb = blockIdx.x;
  const int col = blockIdx.z * 256 + threadIdx.x;
  __shared__ float us[48 * 40];
  float y[48];
#pragma unroll
  for (int i = 0; i < 48; ++i) y[i] = 0.f;
  if (blockIdx.y == 0) {
    for (int i = threadIdx.x; i < 48 * 32; i += 256) us[i] = U2buf[(size_t)bb * 1536 + i];
    __syncthreads();
    const float* V = v2 + (size_t)bb * LL * 1024 + col;
    for (int l = 0; l < LL; ++l) {
      float v = V[(size_t)l * 1024];
#pragma unroll
      for (int i = 0; i < 48; ++i) y[i] = fmaf(us[i * 32 + l], v, y[i]);
    }
    float* Yo = YA + (size_t)bb * 48 * 1024 + col;
#pragma unroll
    for (int i = 0; i < 48; ++i) Yo[(size_t)i * 1024] = y[i];
  } else {
    for (int i = threadIdx.x; i < 48 * 40; i += 256) us[i] = U1buf[(size_t)bb * 1920 + i];
    __syncthreads();
    const float* V = v1 + (size_t)bb * RR * 1024 + col;
    for (int r = 0; r < RR; ++r) {
      float v = V[(size_t)r * 1024];
#pragma unroll
      for (int i = 0; i < 48; ++i) y[i] = fmaf(us[i * 40 + r], v, y[i]);
    }
    float* Yo = YB + (size_t)bb * 48 * 1024 + col;
#pragma unroll
    for (int i = 0; i < 48; ++i) Yo[(size_t)i * 1024] = y[i];
  }
}

// out = (y_A . y_B) / ((sqrt(|y_A|^2)+eps)(sqrt(|y_B|^2)+eps)). grid 2304 x 256
__global__ __launch_bounds__(256) void pair_final(
    const float* __restrict__ YA, const float* __restrict__ YB,
    float* __restrict__ out) {
  const int pair = blockIdx.x;
  const int a = pair / NB2;
  const int b = pair - a * NB2;
  const int t = threadIdx.x;
  const float4* ya = (const float4*)(YA + ((size_t)b * 48 + a) * 1024);
  const float4* yb = (const float4*)(YB + ((size_t)a * 48 + b) * 1024);
  float4 va = ya[t], vb = yb[t];
  float num = va.x * vb.x + va.y * vb.y + va.z * vb.z + va.w * vb.w;
  float n1 = va.x * va.x + va.y * va.y + va.z * va.z + va.w * va.w;
  float n2 = vb.x * vb.x + vb.y * vb.y + vb.z * vb.z + vb.w * vb.w;
#pragma unroll
  for (int off = 32; off; off >>= 1) {
    num += __shfl_down(num, off);
    n1 += __shfl_down(n1, off);
    n2 += __shfl_down(n2, off);
  }
  __shared__ float r3[3][4];
  if ((t & 63) == 0) {
    r3[0][t >> 6] = num; r3[1][t >> 6] = n1; r3[2][t >> 6] = n2;
  }
  __syncthreads();
  if (t == 0) {
    float nu = r3[0][0] + r3[0][1] + r3[0][2] + r3[0][3];
    float s1 = sqrtf(fmaxf(r3[1][0] + r3[1][1] + r3[1][2] + r3[1][3], 0.f));
    float s2 = sqrtf(fmaxf(r3[2][0] + r3[2][1] + r3[2][2] + r3[2][3], 0.f));
    out[pair] = nu / ((s1 + 1e-8f) * (s2 + 1e-8f));
  }
}

extern "C" void kernel_launch(void* const* d_in, const int* in_sizes, int n_in,
                              void* d_out, int out_size, void* d_ws, size_t ws_size,
                              hipStream_t stream) {
  const float* v1    = (const float*)d_in[0];
  const float* v2    = (const float*)d_in[1];
  const float* w_img = (const float*)d_in[2];
  const float* w_txt = (const float*)d_in[3];
  const float* w1a   = (const float*)d_in[4];
  const float* b1a   = (const float*)d_in[5];
  const float* w2a   = (const float*)d_in[6];
  const float* b2a   = (const float*)d_in[7];
  const float* w1b   = (const float*)d_in[8];
  const float* b1b   = (const float*)d_in[9];
  const float* w2b   = (const float*)d_in[10];
  const float* b2b   = (const float*)d_in[11];
  float* out = (float*)d_out;

  // fp32 region (k1/k2 slots unused — kept for layout stability)
  float* ws   = (float*)d_ws;
  float* k1   = ws;                           // 1728*1024 (dead)
  float* k2   = k1 + (size_t)1728 * 1024;     // 1440*1024 (dead)
  float* G2a  = k2 + (size_t)1440 * 1024;     // 1440*1024
  float* G1b  = G2a + (size_t)1440 * 1024;    // 1728*1024
  float* Sbuf = G1b + (size_t)1728 * 1024;    // 1440*1728
  float* Cbuf = Sbuf + (size_t)1440 * 1728;   // 1440*1728 (region reused for YA)
  float* g22  = Cbuf + (size_t)1440 * 1728;   // dead slot -> w2at/w2bt home
  float* g11  = g22 + (size_t)48 * 900;
  (void)k1; (void)k2;

  // split-bf16 fragment region
  unsigned short* fb    = (unsigned short*)(g11 + (size_t)48 * 1296);
  unsigned short* v1f   = fb;                                  // 108 tiles
  unsigned short* v2f   = v1f + (size_t)108 * 32768;           //  92 tiles
  unsigned short* k1f   = v2f + (size_t)92 * 32768;            // 108 tiles
  unsigned short* k2f   = k1f + (size_t)108 * 32768;           //  92 tiles
  unsigned short* wimgf = k2f + (size_t)92 * 32768;            //  64 tiles each
  unsigned short* wtxtf = wimgf + (size_t)64 * 32768;
  unsigned short* w1af  = wtxtf + (size_t)64 * 32768;
  unsigned short* w1bf  = w1af + (size_t)64 * 32768;
  unsigned short* G2aF  = w1bf + (size_t)64 * 32768;           // 48 * 65536 ush
  unsigned short* G1bF  = G2aF + (size_t)48 * 65536;           // 48 * 131072 ush

  // w2 transposed (float4 per col) lives in the DEAD g22 slot — written by
  // conv6 (first kernel), read only by pair_dir.
  float4* w2at = (float4*)g22;                // 1024 float4
  float4* w2bt = w2at + 1024;                 // 1024 float4

  // u buffers ALIAS G2a fp32 (dead after convG; pair_dir runs after convG).
  float* U2buf = G2a;                          // 48*48*32
  float* U1buf = U2buf + (size_t)48 * 48 * 32; // 48*48*40
  // YA ALIASES Cbuf region (never written otherwise): 9.44 MB <= 9.95 MB.
  float* YA = Cbuf;
  // YB ALIASES k1f/k2f frag region (dead after projG_cross): 9.44 MB <= 13.1 MB.
  float* YB = (float*)k1f;

  conv6<<<dim3(864, 6), 256, 0, stream>>>(v1, v2, w_img, w_txt, w1a, w1b,
                                          w2a, w2b,
                                          v1f, v2f, wimgf, wtxtf, w1af, w1bf,
                                          w2at, w2bt);

  projK<<<dim3(16, 14, 2), 128, 0, stream>>>(
      (const bf16x8*)v1f, (const bf16x8*)v2f, (const bf16x8*)wimgf,
      (const bf16x8*)wtxtf, k1f, k2f);

  projG_cross<<<dim3(27, 14, 3), 128, 0, stream>>>(
      (const bf16x8*)v1f, (const bf16x8*)v2f,
      (const bf16x8*)w1af, (const bf16x8*)w1bf,
      (const bf16x8*)k2f, (const bf16x8*)k1f,
      G2a, G1b, Sbuf);

  convG<<<dim3(768, 2), 256, 0, stream>>>(G2a, G1b, G2aF, G1bF);

  pair_dir<<<1152, 256, 0, stream>>>(
      Sbuf, (const bf16x8*)G2aF, (const bf16x8*)G1bF,
      b1a, w2at, b2a, b1b, w2bt, b2b, U1buf, U2buf);
  y_batch<<<dim3(48, 2, 4), 256, 0, stream>>>(v1, v2, U1buf, U2buf, YA, YB);
  pair_final<<<2304, 256, 0, stream>>>(YA, YB, out);
}

// Round 13
// 281.816 us; speedup vs baseline: 1.0748x; 1.0748x over previous
//
#include <hip/hip_runtime.h>

#define D 1024
#define NB1 48
#define NB2 48
#define RR 36
#define LL 30
#define NH 4

typedef short bf16x8 __attribute__((ext_vector_type(8)));
typedef float f32x4 __attribute__((ext_vector_type(4)));
typedef float f32x2 __attribute__((ext_vector_type(2)));
typedef unsigned short u16x8 __attribute__((ext_vector_type(8)));

#define MFMA16(a, b, c) __builtin_amdgcn_mfma_f32_16x16x32_bf16(a, b, c, 0, 0, 0)

__device__ __forceinline__ unsigned short f2bf(float x) {
  unsigned u = __float_as_uint(x);
  u += 0x7FFF + ((u >> 16) & 1);
  return (unsigned short)(u >> 16);
}
__device__ __forceinline__ float bf2f(unsigned short h) {
  return __uint_as_float(((unsigned)h) << 16);
}
__device__ __forceinline__ void split8(const float* v, bf16x8& h8, bf16x8& l8) {
  u16x8 hi, lo;
#pragma unroll
  for (int i = 0; i < 8; ++i) {
    unsigned short h = f2bf(v[i]);
    hi[i] = h;
    lo[i] = f2bf(v[i] - bf2f(h));
  }
  h8 = __builtin_bit_cast(bf16x8, hi);
  l8 = __builtin_bit_cast(bf16x8, lo);
}
__device__ __forceinline__ f32x2 shflx2(f32x2 v, int m) {
  double d = __builtin_bit_cast(double, v);
  d = __shfl_xor(d, m);
  return __builtin_bit_cast(f32x2, d);
}

// ---- fp32 row-major (rows x 1024) -> split-bf16 MFMA fragment layout ----
__device__ __forceinline__ void conv_body(const float* __restrict__ X,
                                          unsigned short* __restrict__ out,
                                          int rows, int g) {
  const int lane = threadIdx.x & 63;
  const int tile = g >> 5, kc = g & 31;
  const int row = tile * 16 + (lane & 15);
  const int k = kc * 32 + (lane >> 4) * 8;
  float v[8];
  if (row < rows) {
    const float4* s = (const float4*)(X + (size_t)row * 1024 + k);
    float4 x0 = s[0], x1 = s[1];
    v[0] = x0.x; v[1] = x0.y; v[2] = x0.z; v[3] = x0.w;
    v[4] = x1.x; v[5] = x1.y; v[6] = x1.z; v[7] = x1.w;
  } else {
#pragma unroll
    for (int i = 0; i < 8; ++i) v[i] = 0.f;
  }
  bf16x8 hi, lo;
  split8(v, hi, lo);
  bf16x8* o = (bf16x8*)(out + (size_t)g * 1024 + lane * 8);
  o[0] = hi;
  o[64] = lo;
}

// 6 input matrices in one launch + w2 transpose (y==0, x<4). grid (864, 6)
__global__ __launch_bounds__(256) void conv6(
    const float* __restrict__ v1, const float* __restrict__ v2,
    const float* __restrict__ wimg, const float* __restrict__ wtxt,
    const float* __restrict__ w1a, const float* __restrict__ w1b,
    const float* __restrict__ w2a, const float* __restrict__ w2b,
    unsigned short* v1f, unsigned short* v2f, unsigned short* wimgf,
    unsigned short* wtxtf, unsigned short* w1af, unsigned short* w1bf,
    float4* __restrict__ w2at, float4* __restrict__ w2bt) {
  if (blockIdx.y == 0 && blockIdx.x < 4) {
    int col = blockIdx.x * 256 + threadIdx.x;
    w2at[col] = make_float4(w2a[col], w2a[1024 + col], w2a[2048 + col], w2a[3072 + col]);
    w2bt[col] = make_float4(w2b[col], w2b[1024 + col], w2b[2048 + col], w2b[3072 + col]);
  }
  const float* X; unsigned short* O; int rows;
  switch (blockIdx.y) {
    case 0: X = v1; O = v1f; rows = 1728; break;
    case 1: X = v2; O = v2f; rows = 1440; break;
    case 2: X = wimg; O = wimgf; rows = 1024; break;
    case 3: X = wtxt; O = wtxtf; rows = 1024; break;
    case 4: X = w1a; O = w1af; rows = 1024; break;
    default: X = w1b; O = w1bf; rows = 1024; break;
  }
  const int tiles = (rows + 15) >> 4;
  const int g = blockIdx.x * 4 + (threadIdx.x >> 6);
  if (g >= tiles * 32) return;
  conv_body(X, O, rows, g);
}

// ---- split-bf16 MFMA GEMM core: 2 waves/block, each 4x4 tiles (128x64 out) ----
#define LOAD_FRAGS(AH, AL, BH, BL)                                              \
  {                                                                             \
    _Pragma("unroll") for (int i = 0; i < 4; ++i) {                             \
      AH[i] = Af[ab[i]]; AL[i] = Af[ab[i] + 64]; ab[i] += 128;                  \
    }                                                                           \
    _Pragma("unroll") for (int j = 0; j < 4; ++j) {                             \
      BH[j] = Bf[bb[j]]; BL[j] = Bf[bb[j] + 64]; bb[j] += 128;                  \
    }                                                                           \
  }

#define MFMA_SET(AH, AL, BH, BL)                                                \
  _Pragma("unroll") for (int i = 0; i < 4; ++i)                                 \
      _Pragma("unroll") for (int j = 0; j < 4; ++j) {                           \
    acc[i][j] = MFMA16(AH[i], BH[j], acc[i][j]);                                \
    acc[i][j] = MFMA16(AL[i], BH[j], acc[i][j]);                                \
    acc[i][j] = MFMA16(AH[i], BL[j], acc[i][j]);                                \
  }

__device__ __forceinline__ void gemm2w_acc(const bf16x8* __restrict__ Af,
                                           const bf16x8* __restrict__ Bf,
                                           int Mtiles, int Ntiles,
                                           int mb, int nb, int lane,
                                           f32x4 (&acc)[4][4]) {
  int ab[4], bb[4];
#pragma unroll
  for (int i = 0; i < 4; ++i) {
    int tm = mb + i; if (tm > Mtiles - 1) tm = Mtiles - 1;
    ab[i] = tm * 4096 + lane;
    int tn = nb + i; if (tn > Ntiles - 1) tn = Ntiles - 1;
    bb[i] = tn * 4096 + lane;
  }
#pragma unroll
  for (int i = 0; i < 4; ++i)
#pragma unroll
    for (int j = 0; j < 4; ++j) acc[i][j] = (f32x4){0.f, 0.f, 0.f, 0.f};

  bf16x8 ahA[4], alA[4], bhA[4], blA[4];
  bf16x8 ahB[4], alB[4], bhB[4], blB[4];
  LOAD_FRAGS(ahA, alA, bhA, blA);
#pragma unroll 1
  for (int kc = 0; kc < 30; kc += 2) {
    LOAD_FRAGS(ahB, alB, bhB, blB);
    MFMA_SET(ahA, alA, bhA, blA);
    LOAD_FRAGS(ahA, alA, bhA, blA);
    MFMA_SET(ahB, alB, bhB, blB);
  }
  LOAD_FRAGS(ahB, alB, bhB, blB);
  MFMA_SET(ahA, alA, bhA, blA);
  MFMA_SET(ahB, alB, bhB, blB);
}

__device__ __forceinline__ void gemm2w_store_fp32(f32x4 (&acc)[4][4],
                                                  float* __restrict__ C,
                                                  int M, int N, float scale,
                                                  int mb, int nb, int lane) {
  const int c16 = lane & 15, q = lane >> 4;
#pragma unroll
  for (int i = 0; i < 4; ++i) {
#pragma unroll
    for (int reg = 0; reg < 4; ++reg) {
      int r = (mb + i) * 16 + q * 4 + reg;
      if (r < M) {
#pragma unroll
        for (int j = 0; j < 4; ++j) {
          int col = (nb + j) * 16 + c16;
          if (col < N) C[(size_t)r * N + col] = acc[i][j][reg] * scale;
        }
      }
    }
  }
}

// 4 projection GEMMs. grid (16, 14, 4) x 128.
// z<2: output split-bf16 k-fragments DIRECTLY (LDS transpose epilogue) — no
// fp32 round-trip. z>=2: fp32 G2a/G1b (consumed by cross_convG's convG part).
__global__ __launch_bounds__(128) void proj_fused(
    const bf16x8* __restrict__ v1f, const bf16x8* __restrict__ v2f,
    const bf16x8* __restrict__ wimgf, const bf16x8* __restrict__ wtxtf,
    const bf16x8* __restrict__ w1af, const bf16x8* __restrict__ w1bf,
    float* G2a, float* G1b,
    unsigned short* k1f, unsigned short* k2f) {
  const int z = blockIdx.z;
  const int lane = threadIdx.x & 63;
  const int w = threadIdx.x >> 6;
  const int mb = blockIdx.y * 8 + w * 4;
  const int nb = blockIdx.x * 4;
  const bf16x8* Af = (z == 0 || z == 3) ? v1f : v2f;
  const bf16x8* Bf = (z == 0) ? wimgf : (z == 1) ? wtxtf : (z == 2) ? w1af : w1bf;
  const int Mt = (z == 0 || z == 3) ? 108 : 90;
  if ((int)blockIdx.y * 8 >= Mt) return;

  __shared__ __align__(16) float tlds[2][4][16][68];

  f32x4 acc[4][4];
  gemm2w_acc(Af, Bf, Mt, 64, mb, nb, lane, acc);

  if (z <= 1) {
    unsigned short* F = z ? k2f : k1f;
    const int c16 = lane & 15, q = lane >> 4;
#pragma unroll
    for (int i = 0; i < 4; ++i)
#pragma unroll
      for (int j = 0; j < 4; ++j)
#pragma unroll
        for (int reg = 0; reg < 4; ++reg)
          tlds[w][i][q * 4 + reg][j * 16 + c16] = acc[i][j][reg];
    __builtin_amdgcn_sched_barrier(0);
    const int r16 = lane & 15, q2 = lane >> 4;
#pragma unroll
    for (int i = 0; i < 4; ++i) {
      if (mb + i < Mt) {
#pragma unroll
        for (int kcl = 0; kcl < 2; ++kcl) {
          const float* rp = &tlds[w][i][r16][kcl * 32 + q2 * 8];
          float4 x0 = *(const float4*)rp;
          float4 x1 = *(const float4*)(rp + 4);
          float v[8];
          v[0] = x0.x; v[1] = x0.y; v[2] = x0.z; v[3] = x0.w;
          v[4] = x1.x; v[5] = x1.y; v[6] = x1.z; v[7] = x1.w;
          bf16x8 hi, lo;
          split8(v, hi, lo);
          size_t g = (size_t)(mb + i) * 32 + (nb >> 1) + kcl;
          bf16x8* o = (bf16x8*)(F + g * 1024 + lane * 8);
          o[0] = hi;
          o[64] = lo;
        }
      }
    }
  } else {
    float* C = (z == 2) ? G2a : G1b;
    const int M = (z == 2) ? 1440 : 1728;
    gemm2w_store_fp32(acc, C, M, 1024, 1.f, mb, nb, lane);
  }
}

// cross_s + convG co-scheduled in ONE 128-thr launch (both depend only on
// proj_fused; cross alone is 324 blocks = 1.27/CU grid-starved). grid 3396.
// bx<324: S = k2*k1^T. bx>=324: convG wave-tasks (2 per block):
// task = plane*3072 + bb*64 + nt, identical math to the verified convG.
__global__ __launch_bounds__(128) void cross_convG(
    const bf16x8* __restrict__ k2f, const bf16x8* __restrict__ k1f,
    const float* __restrict__ G2a, const float* __restrict__ G1b,
    float* __restrict__ Sbuf,
    unsigned short* G2aF, unsigned short* G1bF) {
  const int bx = blockIdx.x;
  const int lane = threadIdx.x & 63, w = threadIdx.x >> 6;
  if (bx < 324) {
    const int x = bx % 27, y = bx / 27;
    const int mb = y * 8 + w * 4;
    const int nb = x * 4;
    f32x4 acc[4][4];
    gemm2w_acc(k2f, k1f, 90, 108, mb, nb, lane, acc);
    gemm2w_store_fp32(acc, Sbuf, 1440, 1728, 0.03125f, mb, nb, lane);
    return;
  }
  const int tid = (bx - 324) * 2 + w;      // [0, 6144)
  const int plane = tid / 3072;
  const int rem = tid - plane * 3072;
  const int bb = rem >> 6, nt = rem & 63;
  const int c = lane & 15, q = lane >> 4;
  if (plane == 0) {
    float v[8];
#pragma unroll
    for (int j = 0; j < 8; ++j) {
      int l = q * 8 + j;
      v[j] = (l < LL) ? G2a[(size_t)(bb * LL + l) * D + nt * 16 + c] : 0.f;
    }
    bf16x8 hi, lo;
    split8(v, hi, lo);
    bf16x8* o = (bf16x8*)(G2aF + ((size_t)(bb * 64 + nt) * 2) * 512 + lane * 8);
    o[0] = hi;
    o[64] = lo;
  } else {
#pragma unroll
    for (int kc = 0; kc < 2; ++kc) {
      float v[8];
#pragma unroll
      for (int j = 0; j < 8; ++j) {
        int r = kc * 32 + q * 8 + j;
        v[j] = (r < RR) ? G1b[(size_t)(bb * RR + r) * D + nt * 16 + c] : 0.f;
      }
      bf16x8 hi, lo;
      split8(v, hi, lo);
      bf16x8* o = (bf16x8*)(G1bF + (((size_t)(bb * 64 + nt) * 2 + kc) * 2) * 512 + lane * 8);
      o[0] = hi;
      o[64] = lo;
    }
  }
}

// -------- wave-per-(pair,dir) kernel: grid 1152 x 256; zero __syncthreads ----
// Block composition: all 4 waves SAME dir + SAME B-matrix; XCD pinning via bx%8
// (R8-verified: FETCH 85->23MB). LDS 24KB (R11-verified): clamped A-rows,
// register-built K-pad.
__global__ __launch_bounds__(256, 4) void pair_dir(
    const float* __restrict__ Sb,
    const bf16x8* __restrict__ G2aF, const bf16x8* __restrict__ G1bF,
    const float* __restrict__ b1a, const float4* __restrict__ w2at, const float* __restrict__ b2a,
    const float* __restrict__ b1b, const float4* __restrict__ w2bt, const float* __restrict__ b2b,
    float* __restrict__ U1buf, float* __restrict__ U2buf) {
  const int t = threadIdx.x, lane = t & 63, w = t >> 6;
  const int bx = blockIdx.x;
  int a, b, dir;
  if (bx < 576) {
    dir = 0;
    const int lo = bx & 7, i = bx >> 3;
    b = lo + 8 * (i % 6);
    a = (i / 6) * 4 + w;
  } else {
    dir = 1;
    const int bx2 = bx - 576;
    const int lo = bx2 & 7, i = bx2 >> 3;
    a = lo + 8 * (i % 6);
    b = (i / 6) * 4 + w;
  }
  const int c16 = lane & 15, q = lane >> 4;

  union WSM {
    struct { float p2s[36][36]; float sa[36][NH]; float qa[36]; } A;   // 5904 B
    struct { float p1s[30][36]; float sbm[30][NH]; float qb[30]; } B;  // 4920 B
  };
  __shared__ __align__(16) WSM sm[4];
  WSM& S = sm[w];

  const float* Sab = Sb + (size_t)(b * LL) * 1728 + a * RR;

  if (dir == 0) {
    // ================= direction A (one wave) =================
    if (lane < RR) { S.A.p2s[lane][30] = 0.f; S.A.p2s[lane][31] = 0.f; }
    __builtin_amdgcn_sched_barrier(0);
    for (int i = lane; i < LL * RR; i += 64) {
      int l = i / RR, r = i - l * RR;
      S.A.p2s[r][l] = Sab[(size_t)l * 1728 + r];
    }
    __builtin_amdgcn_sched_barrier(0);
    if (lane < RR) {
      const int r = lane;
      float m = -1e30f;
      for (int l = 0; l < LL; ++l) m = fmaxf(m, S.A.p2s[r][l]);
      float s = 0.f;
      for (int l = 0; l < LL; ++l) {
        float e = __expf(S.A.p2s[r][l] - m);
        S.A.p2s[r][l] = e;
        s += e;
      }
      float inv = 1.f / s;
      for (int l = 0; l < LL; ++l) S.A.p2s[r][l] *= inv;
    }
    __builtin_amdgcn_sched_barrier(0);

    bf16x8 pAh[3], pAl[3];
#pragma unroll
    for (int mt = 0; mt < 3; ++mt) {
      int rr = mt * 16 + c16;
      if (rr > RR - 1) rr = RR - 1;      // clamped: feeds discarded score rows
      float v[8];
      const float* rp = &S.A.p2s[rr][q * 8];
      float4 x0 = *(const float4*)rp;
      float4 x1 = *(const float4*)(rp + 4);
      v[0] = x0.x; v[1] = x0.y; v[2] = x0.z; v[3] = x0.w;
      v[4] = x1.x; v[5] = x1.y; v[6] = x1.z; v[7] = x1.w;
      split8(v, pAh[mt], pAl[mt]);
    }

    f32x2 sc01[3][4], sc23[3][4];
#pragma unroll
    for (int mt = 0; mt < 3; ++mt)
#pragma unroll
      for (int reg = 0; reg < 4; ++reg) {
        sc01[mt][reg] = (f32x2){0.f, 0.f};
        sc23[mt][reg] = (f32x2){0.f, 0.f};
      }

    const bf16x8* gA = G2aF + (size_t)(b * 64) * 128 + lane;
#pragma unroll 2
    for (int it = 0; it < 64; ++it) {
      const bf16x8* gp = gA + (size_t)it * 128;
      bf16x8 Bh = gp[0], Bl = gp[64];
      const int col = it * 16 + c16;
      float4 wv = w2at[col];
      float bias = b1a[col];
      f32x2 w01 = {wv.x, wv.y}, w23 = {wv.z, wv.w};
#pragma unroll
      for (int mt = 0; mt < 3; ++mt) {
        f32x4 acc = {bias, bias, bias, bias};
        __builtin_amdgcn_s_setprio(1);
        acc = MFMA16(pAh[mt], Bh, acc);
        acc = MFMA16(pAl[mt], Bh, acc);
        acc = MFMA16(pAh[mt], Bl, acc);
        __builtin_amdgcn_s_setprio(0);
#pragma unroll
        for (int reg = 0; reg < 4; ++reg) {
          float hv = fmaxf(acc[reg], 0.f);
          f32x2 hv2 = {hv, hv};
          sc01[mt][reg] += hv2 * w01;
          sc23[mt][reg] += hv2 * w23;
        }
      }
    }
    f32x2 b01 = {b2a[0], b2a[1]}, b23 = {b2a[2], b2a[3]};
#pragma unroll
    for (int mt = 0; mt < 3; ++mt)
#pragma unroll
      for (int reg = 0; reg < 4; ++reg) {
        f32x2 v01 = sc01[mt][reg], v23 = sc23[mt][reg];
#pragma unroll
        for (int m = 1; m <= 8; m <<= 1) {
          v01 += shflx2(v01, m);
          v23 += shflx2(v23, m);
        }
        int row = mt * 16 + q * 4 + reg;
        if (c16 == 0 && row < RR) {
          f32x2* rp = (f32x2*)&S.A.sa[row][0];
          rp[0] = v01 + b01;
          rp[1] = v23 + b23;
        }
      }
    __builtin_amdgcn_sched_barrier(0);
    // head softmax over 36 rows, 16 lanes/head; then qa via cross-head shuffles
    {
      const int h = q, i = c16;
      float x0 = S.A.sa[i][h];
      float x1 = S.A.sa[i + 16][h];
      float x2 = (i < 4) ? S.A.sa[i + 32][h] : -1e30f;
      float m = fmaxf(fmaxf(x0, x1), x2);
      m = fmaxf(m, __shfl_xor(m, 1));
      m = fmaxf(m, __shfl_xor(m, 2));
      m = fmaxf(m, __shfl_xor(m, 4));
      m = fmaxf(m, __shfl_xor(m, 8));
      float e0 = __expf(x0 - m), e1 = __expf(x1 - m);
      float e2 = (i < 4) ? __expf(x2 - m) : 0.f;
      float s = e0 + e1 + e2;
      s += __shfl_xor(s, 1);
      s += __shfl_xor(s, 2);
      s += __shfl_xor(s, 4);
      s += __shfl_xor(s, 8);
      float inv = 0.25f / s;
      float p0 = e0 * inv, p1 = e1 * inv, p2v = e2 * inv;
      p0 += __shfl_xor(p0, 16); p0 += __shfl_xor(p0, 32);
      p1 += __shfl_xor(p1, 16); p1 += __shfl_xor(p1, 32);
      p2v += __shfl_xor(p2v, 16); p2v += __shfl_xor(p2v, 32);
      if (q == 0) {
        S.A.qa[i] = p0;
        S.A.qa[i + 16] = p1;
        if (i < 4) S.A.qa[i + 32] = p2v;
      }
    }
    __builtin_amdgcn_sched_barrier(0);
    // u2[l] = sum_r qa[r] * p2[r][l]
    if (lane < LL) {
      const int l = lane;
      float x = 0.f;
      for (int r = 0; r < RR; ++r) x = fmaf(S.A.qa[r], S.A.p2s[r][l], x);
      U2buf[((size_t)b * 48 + a) * 32 + l] = x;
    }
  } else {
    // ================= direction B (one wave) =================
    for (int i = lane; i < LL * RR; i += 64) {
      int l = i / RR, r = i - l * RR;
      S.B.p1s[l][r] = Sab[(size_t)l * 1728 + r];
    }
    __builtin_amdgcn_sched_barrier(0);
    if (lane < LL) {
      const int l = lane;
      float m = -1e30f;
      for (int r = 0; r < RR; ++r) m = fmaxf(m, S.B.p1s[l][r]);
      float s = 0.f;
      for (int r = 0; r < RR; ++r) {
        float e = __expf(S.B.p1s[l][r] - m);
        S.B.p1s[l][r] = e;
        s += e;
      }
      float inv = 1.f / s;
      for (int r = 0; r < RR; ++r) S.B.p1s[l][r] *= inv;
    }
    __builtin_amdgcn_sched_barrier(0);

    bf16x8 pBh[2][2], pBl[2][2];
#pragma unroll
    for (int mt = 0; mt < 2; ++mt) {
      int rr = mt * 16 + c16;
      if (rr > LL - 1) rr = LL - 1;      // clamped: feeds discarded score rows
      {
        float v[8];
        const float* rp = &S.B.p1s[rr][q * 8];
        float4 x0 = *(const float4*)rp;
        float4 x1 = *(const float4*)(rp + 4);
        v[0] = x0.x; v[1] = x0.y; v[2] = x0.z; v[3] = x0.w;
        v[4] = x1.x; v[5] = x1.y; v[6] = x1.z; v[7] = x1.w;
        split8(v, pBh[mt][0], pBl[mt][0]);
      }
      {
        float v[8];
#pragma unroll
        for (int j = 0; j < 8; ++j) {
          int r = 32 + q * 8 + j;
          v[j] = (r < RR) ? S.B.p1s[rr][r] : 0.f;
        }
        split8(v, pBh[mt][1], pBl[mt][1]);
      }
    }

    f32x2 sc01[2][4], sc23[2][4];
#pragma unroll
    for (int mt = 0; mt < 2; ++mt)
#pragma unroll
      for (int reg = 0; reg < 4; ++reg) {
        sc01[mt][reg] = (f32x2){0.f, 0.f};
        sc23[mt][reg] = (f32x2){0.f, 0.f};
      }

    const bf16x8* gB = G1bF + (size_t)(a * 64) * 256 + lane;
#pragma unroll 2
    for (int it = 0; it < 64; ++it) {
      const bf16x8* gp = gB + (size_t)it * 256;
      bf16x8 B0h = gp[0], B0l = gp[64], B1h = gp[128], B1l = gp[192];
      const int col = it * 16 + c16;
      float4 wv = w2bt[col];
      float bias = b1b[col];
      f32x2 w01 = {wv.x, wv.y}, w23 = {wv.z, wv.w};
#pragma unroll
      for (int mt = 0; mt < 2; ++mt) {
        f32x4 acc = {bias, bias, bias, bias};
        __builtin_amdgcn_s_setprio(1);
        acc = MFMA16(pBh[mt][0], B0h, acc);
        acc = MFMA16(pBl[mt][0], B0h, acc);
        acc = MFMA16(pBh[mt][0], B0l, acc);
        acc = MFMA16(pBh[mt][1], B1h, acc);
        acc = MFMA16(pBl[mt][1], B1h, acc);
        acc = MFMA16(pBh[mt][1], B1l, acc);
        __builtin_amdgcn_s_setprio(0);
#pragma unroll
        for (int reg = 0; reg < 4; ++reg) {
          float hv = fmaxf(acc[reg], 0.f);
          f32x2 hv2 = {hv, hv};
          sc01[mt][reg] += hv2 * w01;
          sc23[mt][reg] += hv2 * w23;
        }
      }
    }
    f32x2 b01 = {b2b[0], b2b[1]}, b23 = {b2b[2], b2b[3]};
#pragma unroll
    for (int mt = 0; mt < 2; ++mt)
#pragma unroll
      for (int reg = 0; reg < 4; ++reg) {
        f32x2 v01 = sc01[mt][reg], v23 = sc23[mt][reg];
#pragma unroll
        for (int m = 1; m <= 8; m <<= 1) {
          v01 += shflx2(v01, m);
          v23 += shflx2(v23, m);
        }
        int row = mt * 16 + q * 4 + reg;
        if (c16 == 0 && row < LL) {
          f32x2* rp = (f32x2*)&S.B.sbm[row][0];
          rp[0] = v01 + b01;
          rp[1] = v23 + b23;
        }
      }
    __builtin_amdgcn_sched_barrier(0);
    // head softmax over 30 rows; qb via cross-head shuffles
    {
      const int h = q, i = c16;
      float x0 = S.B.sbm[i][h];
      float x1 = (i < 14) ? S.B.sbm[i + 16][h] : -1e30f;
      float m = fmaxf(x0, x1);
      m = fmaxf(m, __shfl_xor(m, 1));
      m = fmaxf(m, __shfl_xor(m, 2));
      m = fmaxf(m, __shfl_xor(m, 4));
      m = fmaxf(m, __shfl_xor(m, 8));
      float e0 = __expf(x0 - m);
      float e1 = (i < 14) ? __expf(x1 - m) : 0.f;
      float s = e0 + e1;
      s += __shfl_xor(s, 1);
      s += __shfl_xor(s, 2);
      s += __shfl_xor(s, 4);
      s += __shfl_xor(s, 8);
      float inv = 0.25f / s;
      float p0 = e0 * inv, p1 = e1 * inv;
      p0 += __shfl_xor(p0, 16); p0 += __shfl_xor(p0, 32);
      p1 += __shfl_xor(p1, 16); p1 += __shfl_xor(p1, 32);
      if (q == 0) {
        S.B.qb[i] = p0;
        if (i < 14) S.B.qb[i + 16] = p1;
      }
    }
    __builtin_amdgcn_sched_barrier(0);
    // u1[r] = sum_l qb[l] * p1[l][r]
    if (lane < RR) {
      const int r = lane;
      float x = 0.f;
      for (int l = 0; l < LL; ++l) x = fmaf(S.B.qb[l], S.B.p1s[l][r], x);
      U1buf[((size_t)a * 48 + b) * 40 + r] = x;
    }
  }
}

// Y_A[b] = U2_b(48x30) * V2_b(30x1024) ; Y_B[a] = U1_a(48x36) * V1_a(36x1024)
// grid (48, 2, 4) x 256. Each thread owns one col, 48 accumulators.
__global__ __launch_bounds__(256) void y_batch(
    const float* __restrict__ v1, const float* __restrict__ v2,
    const float* __restrict__ U1buf, const float* __restrict__ U2buf,
    float* __restrict__ YA, float* __restrict__ YB) {
  const int bb = blockIdx.x;
  const int col = blockIdx.z * 256 + threadIdx.x;
  __shared__ float us[48 * 40];
  float y[48];
#pragma unroll
  for (int i = 0; i < 48; ++i) y[i] = 0.f;
  if (blockIdx.y == 0) {
    for (int i = threadIdx.x; i < 48 * 32; i += 256) us[i] = U2buf[(size_t)bb * 1536 + i];
    __syncthreads();
    const float* V = v2 + (size_t)bb * LL * 1024 + col;
    for (int l = 0; l < LL; ++l) {
      float v = V[(size_t)l * 1024];
#pragma unroll
      for (int i = 0; i < 48; ++i) y[i] = fmaf(us[i * 32 + l], v, y[i]);
    }
    float* Yo = YA + (size_t)bb * 48 * 1024 + col;
#pragma unroll
    for (int i = 0; i < 48; ++i) Yo[(size_t)i * 1024] = y[i];
  } else {
    for (int i = threadIdx.x; i < 48 * 40; i += 256) us[i] = U1buf[(size_t)bb * 1920 + i];
    __syncthreads();
    const float* V = v1 + (size_t)bb * RR * 1024 + col;
    for (int r = 0; r < RR; ++r) {
      float v = V[(size_t)r * 1024];
#pragma unroll
      for (int i = 0; i < 48; ++i) y[i] = fmaf(us[i * 40 + r], v, y[i]);
    }
    float* Yo = YB + (size_t)bb * 48 * 1024 + col;
#pragma unroll
    for (int i = 0; i < 48; ++i) Yo[(size_t)i * 1024] = y[i];
  }
}

// out = (y_A . y_B) / ((sqrt(|y_A|^2)+eps)(sqrt(|y_B|^2)+eps)). grid 2304 x 256
__global__ __launch_bounds__(256) void pair_final(
    const float* __restrict__ YA, const float* __restrict__ YB,
    float* __restrict__ out) {
  const int pair = blockIdx.x;
  const int a = pair / NB2;
  const int b = pair - a * NB2;
  const int t = threadIdx.x;
  const float4* ya = (const float4*)(YA + ((size_t)b * 48 + a) * 1024);
  const float4* yb = (const float4*)(YB + ((size_t)a * 48 + b) * 1024);
  float4 va = ya[t], vb = yb[t];
  float num = va.x * vb.x + va.y * vb.y + va.z * vb.z + va.w * vb.w;
  float n1 = va.x * va.x + va.y * va.y + va.z * va.z + va.w * va.w;
  float n2 = vb.x * vb.x + vb.y * vb.y + vb.z * vb.z + vb.w * vb.w;
#pragma unroll
  for (int off = 32; off; off >>= 1) {
    num += __shfl_down(num, off);
    n1 += __shfl_down(n1, off);
    n2 += __shfl_down(n2, off);
  }
  __shared__ float r3[3][4];
  if ((t & 63) == 0) {
    r3[0][t >> 6] = num; r3[1][t >> 6] = n1; r3[2][t >> 6] = n2;
  }
  __syncthreads();
  if (t == 0) {
    float nu = r3[0][0] + r3[0][1] + r3[0][2] + r3[0][3];
    float s1 = sqrtf(fmaxf(r3[1][0] + r3[1][1] + r3[1][2] + r3[1][3], 0.f));
    float s2 = sqrtf(fmaxf(r3[2][0] + r3[2][1] + r3[2][2] + r3[2][3], 0.f));
    out[pair] = nu / ((s1 + 1e-8f) * (s2 + 1e-8f));
  }
}

extern "C" void kernel_launch(void* const* d_in, const int* in_sizes, int n_in,
                              void* d_out, int out_size, void* d_ws, size_t ws_size,
                              hipStream_t stream) {
  const float* v1    = (const float*)d_in[0];
  const float* v2    = (const float*)d_in[1];
  const float* w_img = (const float*)d_in[2];
  const float* w_txt = (const float*)d_in[3];
  const float* w1a   = (const float*)d_in[4];
  const float* b1a   = (const float*)d_in[5];
  const float* w2a   = (const float*)d_in[6];
  const float* b2a   = (const float*)d_in[7];
  const float* w1b   = (const float*)d_in[8];
  const float* b1b   = (const float*)d_in[9];
  const float* w2b   = (const float*)d_in[10];
  const float* b2b   = (const float*)d_in[11];
  float* out = (float*)d_out;

  // fp32 region (k1/k2 slots unused — kept for layout stability)
  float* ws   = (float*)d_ws;
  float* k1   = ws;                           // 1728*1024 (dead)
  float* k2   = k1 + (size_t)1728 * 1024;     // 1440*1024 (dead)
  float* G2a  = k2 + (size_t)1440 * 1024;     // 1440*1024
  float* G1b  = G2a + (size_t)1440 * 1024;    // 1728*1024
  float* Sbuf = G1b + (size_t)1728 * 1024;    // 1440*1728
  float* Cbuf = Sbuf + (size_t)1440 * 1728;   // 1440*1728 (region reused for YA)
  float* g22  = Cbuf + (size_t)1440 * 1728;   // dead slot -> w2at/w2bt home
  float* g11  = g22 + (size_t)48 * 900;
  (void)k1; (void)k2;

  // split-bf16 fragment region
  unsigned short* fb    = (unsigned short*)(g11 + (size_t)48 * 1296);
  unsigned short* v1f   = fb;                                  // 108 tiles
  unsigned short* v2f   = v1f + (size_t)108 * 32768;           //  92 tiles
  unsigned short* k1f   = v2f + (size_t)92 * 32768;            // 108 tiles
  unsigned short* k2f   = k1f + (size_t)108 * 32768;           //  92 tiles
  unsigned short* wimgf = k2f + (size_t)92 * 32768;            //  64 tiles each
  unsigned short* wtxtf = wimgf + (size_t)64 * 32768;
  unsigned short* w1af  = wtxtf + (size_t)64 * 32768;
  unsigned short* w1bf  = w1af + (size_t)64 * 32768;
  unsigned short* G2aF  = w1bf + (size_t)64 * 32768;           // 48 * 65536 ush
  unsigned short* G1bF  = G2aF + (size_t)48 * 65536;           // 48 * 131072 ush

  // w2 transposed (float4 per col) lives in the DEAD g22 slot — written by
  // conv6 (first kernel), read only by pair_dir.
  float4* w2at = (float4*)g22;                // 1024 float4
  float4* w2bt = w2at + 1024;                 // 1024 float4

  // u buffers ALIAS G2a fp32 (dead after cross_convG; pair_dir runs after).
  float* U2buf = G2a;                          // 48*48*32
  float* U1buf = U2buf + (size_t)48 * 48 * 32; // 48*48*40
  // YA ALIASES Cbuf region (never written otherwise): 9.44 MB <= 9.95 MB.
  float* YA = Cbuf;
  // YB ALIASES k1f/k2f frag region (dead after cross_convG): 9.44 MB <= 13.1 MB.
  float* YB = (float*)k1f;

  conv6<<<dim3(864, 6), 256, 0, stream>>>(v1, v2, w_img, w_txt, w1a, w1b,
                                          w2a, w2b,
                                          v1f, v2f, wimgf, wtxtf, w1af, w1bf,
                                          w2at, w2bt);

  proj_fused<<<dim3(16, 14, 4), 128, 0, stream>>>(
      (const bf16x8*)v1f, (const bf16x8*)v2f, (const bf16x8*)wimgf,
      (const bf16x8*)wtxtf, (const bf16x8*)w1af, (const bf16x8*)w1bf,
      G2a, G1b, k1f, k2f);

  cross_convG<<<3396, 128, 0, stream>>>(
      (const bf16x8*)k2f, (const bf16x8*)k1f, G2a, G1b,
      Sbuf, G2aF, G1bF);

  pair_dir<<<1152, 256, 0, stream>>>(
      Sbuf, (const bf16x8*)G2aF, (const bf16x8*)G1bF,
      b1a, w2at, b2a, b1b, w2bt, b2b, U1buf, U2buf);
  y_batch<<<dim3(48, 2, 4), 256, 0, stream>>>(v1, v2, U1buf, U2buf, YA, YB);
  pair_final<<<2304, 256, 0, stream>>>(YA, YB, out);
}

// Round 14
// 279.684 us; speedup vs baseline: 1.0830x; 1.0076x over previous
//
#include <hip/hip_runtime.h>

#define D 1024
#define NB1 48
#define NB2 48
#define RR 36
#define LL 30
#define NH 4

typedef short bf16x8 __attribute__((ext_vector_type(8)));
typedef float f32x4 __attribute__((ext_vector_type(4)));
typedef float f32x2 __attribute__((ext_vector_type(2)));
typedef unsigned short u16x8 __attribute__((ext_vector_type(8)));

#define MFMA16(a, b, c) __builtin_amdgcn_mfma_f32_16x16x32_bf16(a, b, c, 0, 0, 0)

__device__ __forceinline__ unsigned short f2bf(float x) {
  unsigned u = __float_as_uint(x);
  u += 0x7FFF + ((u >> 16) & 1);
  return (unsigned short)(u >> 16);
}
__device__ __forceinline__ float bf2f(unsigned short h) {
  return __uint_as_float(((unsigned)h) << 16);
}
__device__ __forceinline__ void split8(const float* v, bf16x8& h8, bf16x8& l8) {
  u16x8 hi, lo;
#pragma unroll
  for (int i = 0; i < 8; ++i) {
    unsigned short h = f2bf(v[i]);
    hi[i] = h;
    lo[i] = f2bf(v[i] - bf2f(h));
  }
  h8 = __builtin_bit_cast(bf16x8, hi);
  l8 = __builtin_bit_cast(bf16x8, lo);
}
__device__ __forceinline__ f32x2 shflx2(f32x2 v, int m) {
  double d = __builtin_bit_cast(double, v);
  d = __shfl_xor(d, m);
  return __builtin_bit_cast(f32x2, d);
}

// ---- fp32 row-major (rows x 1024) -> split-bf16 MFMA fragment layout ----
__device__ __forceinline__ void conv_body(const float* __restrict__ X,
                                          unsigned short* __restrict__ out,
                                          int rows, int g) {
  const int lane = threadIdx.x & 63;
  const int tile = g >> 5, kc = g & 31;
  const int row = tile * 16 + (lane & 15);
  const int k = kc * 32 + (lane >> 4) * 8;
  float v[8];
  if (row < rows) {
    const float4* s = (const float4*)(X + (size_t)row * 1024 + k);
    float4 x0 = s[0], x1 = s[1];
    v[0] = x0.x; v[1] = x0.y; v[2] = x0.z; v[3] = x0.w;
    v[4] = x1.x; v[5] = x1.y; v[6] = x1.z; v[7] = x1.w;
  } else {
#pragma unroll
    for (int i = 0; i < 8; ++i) v[i] = 0.f;
  }
  bf16x8 hi, lo;
  split8(v, hi, lo);
  bf16x8* o = (bf16x8*)(out + (size_t)g * 1024 + lane * 8);
  o[0] = hi;
  o[64] = lo;
}

// 6 input matrices in one launch + w2 transpose (y==0, x<4). grid (864, 6)
__global__ __launch_bounds__(256) void conv6(
    const float* __restrict__ v1, const float* __restrict__ v2,
    const float* __restrict__ wimg, const float* __restrict__ wtxt,
    const float* __restrict__ w1a, const float* __restrict__ w1b,
    const float* __restrict__ w2a, const float* __restrict__ w2b,
    unsigned short* v1f, unsigned short* v2f, unsigned short* wimgf,
    unsigned short* wtxtf, unsigned short* w1af, unsigned short* w1bf,
    float4* __restrict__ w2at, float4* __restrict__ w2bt) {
  if (blockIdx.y == 0 && blockIdx.x < 4) {
    int col = blockIdx.x * 256 + threadIdx.x;
    w2at[col] = make_float4(w2a[col], w2a[1024 + col], w2a[2048 + col], w2a[3072 + col]);
    w2bt[col] = make_float4(w2b[col], w2b[1024 + col], w2b[2048 + col], w2b[3072 + col]);
  }
  const float* X; unsigned short* O; int rows;
  switch (blockIdx.y) {
    case 0: X = v1; O = v1f; rows = 1728; break;
    case 1: X = v2; O = v2f; rows = 1440; break;
    case 2: X = wimg; O = wimgf; rows = 1024; break;
    case 3: X = wtxt; O = wtxtf; rows = 1024; break;
    case 4: X = w1a; O = w1af; rows = 1024; break;
    default: X = w1b; O = w1bf; rows = 1024; break;
  }
  const int tiles = (rows + 15) >> 4;
  const int g = blockIdx.x * 4 + (threadIdx.x >> 6);
  if (g >= tiles * 32) return;
  conv_body(X, O, rows, g);
}

// ---- split-bf16 MFMA GEMM core: 2 waves/block, each 4x4 tiles (128x64 out) ----
#define LOAD_FRAGS(AH, AL, BH, BL)                                              \
  {                                                                             \
    _Pragma("unroll") for (int i = 0; i < 4; ++i) {                             \
      AH[i] = Af[ab[i]]; AL[i] = Af[ab[i] + 64]; ab[i] += 128;                  \
    }                                                                           \
    _Pragma("unroll") for (int j = 0; j < 4; ++j) {                             \
      BH[j] = Bf[bb[j]]; BL[j] = Bf[bb[j] + 64]; bb[j] += 128;                  \
    }                                                                           \
  }

#define MFMA_SET(AH, AL, BH, BL)                                                \
  _Pragma("unroll") for (int i = 0; i < 4; ++i)                                 \
      _Pragma("unroll") for (int j = 0; j < 4; ++j) {                           \
    acc[i][j] = MFMA16(AH[i], BH[j], acc[i][j]);                                \
    acc[i][j] = MFMA16(AL[i], BH[j], acc[i][j]);                                \
    acc[i][j] = MFMA16(AH[i], BL[j], acc[i][j]);                                \
  }

__device__ __forceinline__ void gemm2w_acc(const bf16x8* __restrict__ Af,
                                           const bf16x8* __restrict__ Bf,
                                           int Mtiles, int Ntiles,
                                           int mb, int nb, int lane,
                                           f32x4 (&acc)[4][4]) {
  int ab[4], bb[4];
#pragma unroll
  for (int i = 0; i < 4; ++i) {
    int tm = mb + i; if (tm > Mtiles - 1) tm = Mtiles - 1;
    ab[i] = tm * 4096 + lane;
    int tn = nb + i; if (tn > Ntiles - 1) tn = Ntiles - 1;
    bb[i] = tn * 4096 + lane;
  }
#pragma unroll
  for (int i = 0; i < 4; ++i)
#pragma unroll
    for (int j = 0; j < 4; ++j) acc[i][j] = (f32x4){0.f, 0.f, 0.f, 0.f};

  bf16x8 ahA[4], alA[4], bhA[4], blA[4];
  bf16x8 ahB[4], alB[4], bhB[4], blB[4];
  LOAD_FRAGS(ahA, alA, bhA, blA);
#pragma unroll 1
  for (int kc = 0; kc < 30; kc += 2) {
    LOAD_FRAGS(ahB, alB, bhB, blB);
    MFMA_SET(ahA, alA, bhA, blA);
    LOAD_FRAGS(ahA, alA, bhA, blA);
    MFMA_SET(ahB, alB, bhB, blB);
  }
  LOAD_FRAGS(ahB, alB, bhB, blB);
  MFMA_SET(ahA, alA, bhA, blA);
  MFMA_SET(ahB, alB, bhB, blB);
}

__device__ __forceinline__ void gemm2w_store_fp32(f32x4 (&acc)[4][4],
                                                  float* __restrict__ C,
                                                  int M, int N, float scale,
                                                  int mb, int nb, int lane) {
  const int c16 = lane & 15, q = lane >> 4;
#pragma unroll
  for (int i = 0; i < 4; ++i) {
#pragma unroll
    for (int reg = 0; reg < 4; ++reg) {
      int r = (mb + i) * 16 + q * 4 + reg;
      if (r < M) {
#pragma unroll
        for (int j = 0; j < 4; ++j) {
          int col = (nb + j) * 16 + c16;
          if (col < N) C[(size_t)r * N + col] = acc[i][j][reg] * scale;
        }
      }
    }
  }
}

// 4 projection GEMMs. grid (16, 14, 4) x 128.
// z<2: output split-bf16 k-fragments DIRECTLY (LDS transpose epilogue) — no
// fp32 round-trip. z>=2: fp32 G2a/G1b (consumed by cross_convG's convG part).
__global__ __launch_bounds__(128) void proj_fused(
    const bf16x8* __restrict__ v1f, const bf16x8* __restrict__ v2f,
    const bf16x8* __restrict__ wimgf, const bf16x8* __restrict__ wtxtf,
    const bf16x8* __restrict__ w1af, const bf16x8* __restrict__ w1bf,
    float* G2a, float* G1b,
    unsigned short* k1f, unsigned short* k2f) {
  const int z = blockIdx.z;
  const int lane = threadIdx.x & 63;
  const int w = threadIdx.x >> 6;
  const int mb = blockIdx.y * 8 + w * 4;
  const int nb = blockIdx.x * 4;
  const bf16x8* Af = (z == 0 || z == 3) ? v1f : v2f;
  const bf16x8* Bf = (z == 0) ? wimgf : (z == 1) ? wtxtf : (z == 2) ? w1af : w1bf;
  const int Mt = (z == 0 || z == 3) ? 108 : 90;
  if ((int)blockIdx.y * 8 >= Mt) return;

  __shared__ __align__(16) float tlds[2][4][16][68];

  f32x4 acc[4][4];
  gemm2w_acc(Af, Bf, Mt, 64, mb, nb, lane, acc);

  if (z <= 1) {
    unsigned short* F = z ? k2f : k1f;
    const int c16 = lane & 15, q = lane >> 4;
#pragma unroll
    for (int i = 0; i < 4; ++i)
#pragma unroll
      for (int j = 0; j < 4; ++j)
#pragma unroll
        for (int reg = 0; reg < 4; ++reg)
          tlds[w][i][q * 4 + reg][j * 16 + c16] = acc[i][j][reg];
    __builtin_amdgcn_sched_barrier(0);
    const int r16 = lane & 15, q2 = lane >> 4;
#pragma unroll
    for (int i = 0; i < 4; ++i) {
      if (mb + i < Mt) {
#pragma unroll
        for (int kcl = 0; kcl < 2; ++kcl) {
          const float* rp = &tlds[w][i][r16][kcl * 32 + q2 * 8];
          float4 x0 = *(const float4*)rp;
          float4 x1 = *(const float4*)(rp + 4);
          float v[8];
          v[0] = x0.x; v[1] = x0.y; v[2] = x0.z; v[3] = x0.w;
          v[4] = x1.x; v[5] = x1.y; v[6] = x1.z; v[7] = x1.w;
          bf16x8 hi, lo;
          split8(v, hi, lo);
          size_t g = (size_t)(mb + i) * 32 + (nb >> 1) + kcl;
          bf16x8* o = (bf16x8*)(F + g * 1024 + lane * 8);
          o[0] = hi;
          o[64] = lo;
        }
      }
    }
  } else {
    float* C = (z == 2) ? G2a : G1b;
    const int M = (z == 2) ? 1440 : 1728;
    gemm2w_store_fp32(acc, C, M, 1024, 1.f, mb, nb, lane);
  }
}

// cross_s + convG co-scheduled in ONE 128-thr launch (both depend only on
// proj_fused; cross alone is 324 blocks = 1.27/CU grid-starved). grid 3396.
// bx<324: S = k2*k1^T. bx>=324: convG wave-tasks (2 per block):
// task = plane*3072 + bb*64 + nt, identical math to the verified convG.
__global__ __launch_bounds__(128) void cross_convG(
    const bf16x8* __restrict__ k2f, const bf16x8* __restrict__ k1f,
    const float* __restrict__ G2a, const float* __restrict__ G1b,
    float* __restrict__ Sbuf,
    unsigned short* G2aF, unsigned short* G1bF) {
  const int bx = blockIdx.x;
  const int lane = threadIdx.x & 63, w = threadIdx.x >> 6;
  if (bx < 324) {
    const int x = bx % 27, y = bx / 27;
    const int mb = y * 8 + w * 4;
    const int nb = x * 4;
    f32x4 acc[4][4];
    gemm2w_acc(k2f, k1f, 90, 108, mb, nb, lane, acc);
    gemm2w_store_fp32(acc, Sbuf, 1440, 1728, 0.03125f, mb, nb, lane);
    return;
  }
  const int tid = (bx - 324) * 2 + w;      // [0, 6144)
  const int plane = tid / 3072;
  const int rem = tid - plane * 3072;
  const int bb = rem >> 6, nt = rem & 63;
  const int c = lane & 15, q = lane >> 4;
  if (plane == 0) {
    float v[8];
#pragma unroll
    for (int j = 0; j < 8; ++j) {
      int l = q * 8 + j;
      v[j] = (l < LL) ? G2a[(size_t)(bb * LL + l) * D + nt * 16 + c] : 0.f;
    }
    bf16x8 hi, lo;
    split8(v, hi, lo);
    bf16x8* o = (bf16x8*)(G2aF + ((size_t)(bb * 64 + nt) * 2) * 512 + lane * 8);
    o[0] = hi;
    o[64] = lo;
  } else {
#pragma unroll
    for (int kc = 0; kc < 2; ++kc) {
      float v[8];
#pragma unroll
      for (int j = 0; j < 8; ++j) {
        int r = kc * 32 + q * 8 + j;
        v[j] = (r < RR) ? G1b[(size_t)(bb * RR + r) * D + nt * 16 + c] : 0.f;
      }
      bf16x8 hi, lo;
      split8(v, hi, lo);
      bf16x8* o = (bf16x8*)(G1bF + (((size_t)(bb * 64 + nt) * 2 + kc) * 2) * 512 + lane * 8);
      o[0] = hi;
      o[64] = lo;
    }
  }
}

// -------- wave-per-(pair,dir) kernel: grid 1152 x 256; zero __syncthreads ----
// Block composition: all 4 waves SAME dir + SAME B-matrix; XCD pinning via bx%8
// (R8-verified: FETCH 85->23MB). LDS 24KB (R11-verified): clamped A-rows,
// register-built K-pad. Hot loops unroll 4 (deeper load-ahead; VGPR headroom
// exists: 60 base, LDS caps blocks/CU not VGPR).
__global__ __launch_bounds__(256, 4) void pair_dir(
    const float* __restrict__ Sb,
    const bf16x8* __restrict__ G2aF, const bf16x8* __restrict__ G1bF,
    const float* __restrict__ b1a, const float4* __restrict__ w2at, const float* __restrict__ b2a,
    const float* __restrict__ b1b, const float4* __restrict__ w2bt, const float* __restrict__ b2b,
    float* __restrict__ U1buf, float* __restrict__ U2buf) {
  const int t = threadIdx.x, lane = t & 63, w = t >> 6;
  const int bx = blockIdx.x;
  int a, b, dir;
  if (bx < 576) {
    dir = 0;
    const int lo = bx & 7, i = bx >> 3;
    b = lo + 8 * (i % 6);
    a = (i / 6) * 4 + w;
  } else {
    dir = 1;
    const int bx2 = bx - 576;
    const int lo = bx2 & 7, i = bx2 >> 3;
    a = lo + 8 * (i % 6);
    b = (i / 6) * 4 + w;
  }
  const int c16 = lane & 15, q = lane >> 4;

  union WSM {
    struct { float p2s[36][36]; float sa[36][NH]; float qa[36]; } A;   // 5904 B
    struct { float p1s[30][36]; float sbm[30][NH]; float qb[30]; } B;  // 4920 B
  };
  __shared__ __align__(16) WSM sm[4];
  WSM& S = sm[w];

  const float* Sab = Sb + (size_t)(b * LL) * 1728 + a * RR;

  if (dir == 0) {
    // ================= direction A (one wave) =================
    if (lane < RR) { S.A.p2s[lane][30] = 0.f; S.A.p2s[lane][31] = 0.f; }
    __builtin_amdgcn_sched_barrier(0);
    for (int i = lane; i < LL * RR; i += 64) {
      int l = i / RR, r = i - l * RR;
      S.A.p2s[r][l] = Sab[(size_t)l * 1728 + r];
    }
    __builtin_amdgcn_sched_barrier(0);
    if (lane < RR) {
      const int r = lane;
      float m = -1e30f;
      for (int l = 0; l < LL; ++l) m = fmaxf(m, S.A.p2s[r][l]);
      float s = 0.f;
      for (int l = 0; l < LL; ++l) {
        float e = __expf(S.A.p2s[r][l] - m);
        S.A.p2s[r][l] = e;
        s += e;
      }
      float inv = 1.f / s;
      for (int l = 0; l < LL; ++l) S.A.p2s[r][l] *= inv;
    }
    __builtin_amdgcn_sched_barrier(0);

    bf16x8 pAh[3], pAl[3];
#pragma unroll
    for (int mt = 0; mt < 3; ++mt) {
      int rr = mt * 16 + c16;
      if (rr > RR - 1) rr = RR - 1;      // clamped: feeds discarded score rows
      float v[8];
      const float* rp = &S.A.p2s[rr][q * 8];
      float4 x0 = *(const float4*)rp;
      float4 x1 = *(const float4*)(rp + 4);
      v[0] = x0.x; v[1] = x0.y; v[2] = x0.z; v[3] = x0.w;
      v[4] = x1.x; v[5] = x1.y; v[6] = x1.z; v[7] = x1.w;
      split8(v, pAh[mt], pAl[mt]);
    }

    f32x2 sc01[3][4], sc23[3][4];
#pragma unroll
    for (int mt = 0; mt < 3; ++mt)
#pragma unroll
      for (int reg = 0; reg < 4; ++reg) {
        sc01[mt][reg] = (f32x2){0.f, 0.f};
        sc23[mt][reg] = (f32x2){0.f, 0.f};
      }

    const bf16x8* gA = G2aF + (size_t)(b * 64) * 128 + lane;
#pragma unroll 4
    for (int it = 0; it < 64; ++it) {
      const bf16x8* gp = gA + (size_t)it * 128;
      bf16x8 Bh = gp[0], Bl = gp[64];
      const int col = it * 16 + c16;
      float4 wv = w2at[col];
      float bias = b1a[col];
      f32x2 w01 = {wv.x, wv.y}, w23 = {wv.z, wv.w};
#pragma unroll
      for (int mt = 0; mt < 3; ++mt) {
        f32x4 acc = {bias, bias, bias, bias};
        __builtin_amdgcn_s_setprio(1);
        acc = MFMA16(pAh[mt], Bh, acc);
        acc = MFMA16(pAl[mt], Bh, acc);
        acc = MFMA16(pAh[mt], Bl, acc);
        __builtin_amdgcn_s_setprio(0);
#pragma unroll
        for (int reg = 0; reg < 4; ++reg) {
          float hv = fmaxf(acc[reg], 0.f);
          f32x2 hv2 = {hv, hv};
          sc01[mt][reg] += hv2 * w01;
          sc23[mt][reg] += hv2 * w23;
        }
      }
    }
    f32x2 b01 = {b2a[0], b2a[1]}, b23 = {b2a[2], b2a[3]};
#pragma unroll
    for (int mt = 0; mt < 3; ++mt)
#pragma unroll
      for (int reg = 0; reg < 4; ++reg) {
        f32x2 v01 = sc01[mt][reg], v23 = sc23[mt][reg];
#pragma unroll
        for (int m = 1; m <= 8; m <<= 1) {
          v01 += shflx2(v01, m);
          v23 += shflx2(v23, m);
        }
        int row = mt * 16 + q * 4 + reg;
        if (c16 == 0 && row < RR) {
          f32x2* rp = (f32x2*)&S.A.sa[row][0];
          rp[0] = v01 + b01;
          rp[1] = v23 + b23;
        }
      }
    __builtin_amdgcn_sched_barrier(0);
    // head softmax over 36 rows, 16 lanes/head; then qa via cross-head shuffles
    {
      const int h = q, i = c16;
      float x0 = S.A.sa[i][h];
      float x1 = S.A.sa[i + 16][h];
      float x2 = (i < 4) ? S.A.sa[i + 32][h] : -1e30f;
      float m = fmaxf(fmaxf(x0, x1), x2);
      m = fmaxf(m, __shfl_xor(m, 1));
      m = fmaxf(m, __shfl_xor(m, 2));
      m = fmaxf(m, __shfl_xor(m, 4));
      m = fmaxf(m, __shfl_xor(m, 8));
      float e0 = __expf(x0 - m), e1 = __expf(x1 - m);
      float e2 = (i < 4) ? __expf(x2 - m) : 0.f;
      float s = e0 + e1 + e2;
      s += __shfl_xor(s, 1);
      s += __shfl_xor(s, 2);
      s += __shfl_xor(s, 4);
      s += __shfl_xor(s, 8);
      float inv = 0.25f / s;
      float p0 = e0 * inv, p1 = e1 * inv, p2v = e2 * inv;
      p0 += __shfl_xor(p0, 16); p0 += __shfl_xor(p0, 32);
      p1 += __shfl_xor(p1, 16); p1 += __shfl_xor(p1, 32);
      p2v += __shfl_xor(p2v, 16); p2v += __shfl_xor(p2v, 32);
      if (q == 0) {
        S.A.qa[i] = p0;
        S.A.qa[i + 16] = p1;
        if (i < 4) S.A.qa[i + 32] = p2v;
      }
    }
    __builtin_amdgcn_sched_barrier(0);
    // u2[l] = sum_r qa[r] * p2[r][l]
    if (lane < LL) {
      const int l = lane;
      float x = 0.f;
      for (int r = 0; r < RR; ++r) x = fmaf(S.A.qa[r], S.A.p2s[r][l], x);
      U2buf[((size_t)b * 48 + a) * 32 + l] = x;
    }
  } else {
    // ================= direction B (one wave) =================
    for (int i = lane; i < LL * RR; i += 64) {
      int l = i / RR, r = i - l * RR;
      S.B.p1s[l][r] = Sab[(size_t)l * 1728 + r];
    }
    __builtin_amdgcn_sched_barrier(0);
    if (lane < LL) {
      const int l = lane;
      float m = -1e30f;
      for (int r = 0; r < RR; ++r) m = fmaxf(m, S.B.p1s[l][r]);
      float s = 0.f;
      for (int r = 0; r < RR; ++r) {
        float e = __expf(S.B.p1s[l][r] - m);
        S.B.p1s[l][r] = e;
        s += e;
      }
      float inv = 1.f / s;
      for (int r = 0; r < RR; ++r) S.B.p1s[l][r] *= inv;
    }
    __builtin_amdgcn_sched_barrier(0);

    bf16x8 pBh[2][2], pBl[2][2];
#pragma unroll
    for (int mt = 0; mt < 2; ++mt) {
      int rr = mt * 16 + c16;
      if (rr > LL - 1) rr = LL - 1;      // clamped: feeds discarded score rows
      {
        float v[8];
        const float* rp = &S.B.p1s[rr][q * 8];
        float4 x0 = *(const float4*)rp;
        float4 x1 = *(const float4*)(rp + 4);
        v[0] = x0.x; v[1] = x0.y; v[2] = x0.z; v[3] = x0.w;
        v[4] = x1.x; v[5] = x1.y; v[6] = x1.z; v[7] = x1.w;
        split8(v, pBh[mt][0], pBl[mt][0]);
      }
      {
        float v[8];
#pragma unroll
        for (int j = 0; j < 8; ++j) {
          int r = 32 + q * 8 + j;
          v[j] = (r < RR) ? S.B.p1s[rr][r] : 0.f;
        }
        split8(v, pBh[mt][1], pBl[mt][1]);
      }
    }

    f32x2 sc01[2][4], sc23[2][4];
#pragma unroll
    for (int mt = 0; mt < 2; ++mt)
#pragma unroll
      for (int reg = 0; reg < 4; ++reg) {
        sc01[mt][reg] = (f32x2){0.f, 0.f};
        sc23[mt][reg] = (f32x2){0.f, 0.f};
      }

    const bf16x8* gB = G1bF + (size_t)(a * 64) * 256 + lane;
#pragma unroll 4
    for (int it = 0; it < 64; ++it) {
      const bf16x8* gp = gB + (size_t)it * 256;
      bf16x8 B0h = gp[0], B0l = gp[64], B1h = gp[128], B1l = gp[192];
      const int col = it * 16 + c16;
      float4 wv = w2bt[col];
      float bias = b1b[col];
      f32x2 w01 = {wv.x, wv.y}, w23 = {wv.z, wv.w};
#pragma unroll
      for (int mt = 0; mt < 2; ++mt) {
        f32x4 acc = {bias, bias, bias, bias};
        __builtin_amdgcn_s_setprio(1);
        acc = MFMA16(pBh[mt][0], B0h, acc);
        acc = MFMA16(pBl[mt][0], B0h, acc);
        acc = MFMA16(pBh[mt][0], B0l, acc);
        acc = MFMA16(pBh[mt][1], B1h, acc);
        acc = MFMA16(pBl[mt][1], B1h, acc);
        acc = MFMA16(pBh[mt][1], B1l, acc);
        __builtin_amdgcn_s_setprio(0);
#pragma unroll
        for (int reg = 0; reg < 4; ++reg) {
          float hv = fmaxf(acc[reg], 0.f);
          f32x2 hv2 = {hv, hv};
          sc01[mt][reg] += hv2 * w01;
          sc23[mt][reg] += hv2 * w23;
        }
      }
    }
    f32x2 b01 = {b2b[0], b2b[1]}, b23 = {b2b[2], b2b[3]};
#pragma unroll
    for (int mt = 0; mt < 2; ++mt)
#pragma unroll
      for (int reg = 0; reg < 4; ++reg) {
        f32x2 v01 = sc01[mt][reg], v23 = sc23[mt][reg];
#pragma unroll
        for (int m = 1; m <= 8; m <<= 1) {
          v01 += shflx2(v01, m);
          v23 += shflx2(v23, m);
        }
        int row = mt * 16 + q * 4 + reg;
        if (c16 == 0 && row < LL) {
          f32x2* rp = (f32x2*)&S.B.sbm[row][0];
          rp[0] = v01 + b01;
          rp[1] = v23 + b23;
        }
      }
    __builtin_amdgcn_sched_barrier(0);
    // head softmax over 30 rows; qb via cross-head shuffles
    {
      const int h = q, i = c16;
      float x0 = S.B.sbm[i][h];
      float x1 = (i < 14) ? S.B.sbm[i + 16][h] : -1e30f;
      float m = fmaxf(x0, x1);
      m = fmaxf(m, __shfl_xor(m, 1));
      m = fmaxf(m, __shfl_xor(m, 2));
      m = fmaxf(m, __shfl_xor(m, 4));
      m = fmaxf(m, __shfl_xor(m, 8));
      float e0 = __expf(x0 - m);
      float e1 = (i < 14) ? __expf(x1 - m) : 0.f;
      float s = e0 + e1;
      s += __shfl_xor(s, 1);
      s += __shfl_xor(s, 2);
      s += __shfl_xor(s, 4);
      s += __shfl_xor(s, 8);
      float inv = 0.25f / s;
      float p0 = e0 * inv, p1 = e1 * inv;
      p0 += __shfl_xor(p0, 16); p0 += __shfl_xor(p0, 32);
      p1 += __shfl_xor(p1, 16); p1 += __shfl_xor(p1, 32);
      if (q == 0) {
        S.B.qb[i] = p0;
        if (i < 14) S.B.qb[i + 16] = p1;
      }
    }
    __builtin_amdgcn_sched_barrier(0);
    // u1[r] = sum_l qb[l] * p1[l][r]
    if (lane < RR) {
      const int r = lane;
      float x = 0.f;
      for (int l = 0; l < LL; ++l) x = fmaf(S.B.qb[l], S.B.p1s[l][r], x);
      U1buf[((size_t)a * 48 + b) * 40 + r] = x;
    }
  }
}

// Y_A[b] = U2_b(48x30) * V2_b(30x1024) ; Y_B[a] = U1_a(48x36) * V1_a(36x1024)
// grid (48, 2, 4) x 256. Each thread owns one col, 48 accumulators.
__global__ __launch_bounds__(256) void y_batch(
    const float* __restrict__ v1, const float* __restrict__ v2,
    const float* __restrict__ U1buf, const float* __restrict__ U2buf,
    float* __restrict__ YA, float* __restrict__ YB) {
  const int bb = blockIdx.x;
  const int col = blockIdx.z * 256 + threadIdx.x;
  __shared__ float us[48 * 40];
  float y[48];
#pragma unroll
  for (int i = 0; i < 48; ++i) y[i] = 0.f;
  if (blockIdx.y == 0) {
    for (int i = threadIdx.x; i < 48 * 32; i += 256) us[i] = U2buf[(size_t)bb * 1536 + i];
    __syncthreads();
    const float* V = v2 + (size_t)bb * LL * 1024 + col;
    for (int l = 0; l < LL; ++l) {
      float v = V[(size_t)l * 1024];
#pragma unroll
      for (int i = 0; i < 48; ++i) y[i] = fmaf(us[i * 32 + l], v, y[i]);
    }
    float* Yo = YA + (size_t)bb * 48 * 1024 + col;
#pragma unroll
    for (int i = 0; i < 48; ++i) Yo[(size_t)i * 1024] = y[i];
  } else {
    for (int i = threadIdx.x; i < 48 * 40; i += 256) us[i] = U1buf[(size_t)bb * 1920 + i];
    __syncthreads();
    const float* V = v1 + (size_t)bb * RR * 1024 + col;
    for (int r = 0; r < RR; ++r) {
      float v = V[(size_t)r * 1024];
#pragma unroll
      for (int i = 0; i < 48; ++i) y[i] = fmaf(us[i * 40 + r], v, y[i]);
    }
    float* Yo = YB + (size_t)bb * 48 * 1024 + col;
#pragma unroll
    for (int i = 0; i < 48; ++i) Yo[(size_t)i * 1024] = y[i];
  }
}

// out = (y_A . y_B) / ((sqrt(|y_A|^2)+eps)(sqrt(|y_B|^2)+eps)). grid 2304 x 256
__global__ __launch_bounds__(256) void pair_final(
    const float* __restrict__ YA, const float* __restrict__ YB,
    float* __restrict__ out) {
  const int pair = blockIdx.x;
  const int a = pair / NB2;
  const int b = pair - a * NB2;
  const int t = threadIdx.x;
  const float4* ya = (const float4*)(YA + ((size_t)b * 48 + a) * 1024);
  const float4* yb = (const float4*)(YB + ((size_t)a * 48 + b) * 1024);
  float4 va = ya[t], vb = yb[t];
  float num = va.x * vb.x + va.y * vb.y + va.z * vb.z + va.w * vb.w;
  float n1 = va.x * va.x + va.y * va.y + va.z * va.z + va.w * va.w;
  float n2 = vb.x * vb.x + vb.y * vb.y + vb.z * vb.z + vb.w * vb.w;
#pragma unroll
  for (int off = 32; off; off >>= 1) {
    num += __shfl_down(num, off);
    n1 += __shfl_down(n1, off);
    n2 += __shfl_down(n2, off);
  }
  __shared__ float r3[3][4];
  if ((t & 63) == 0) {
    r3[0][t >> 6] = num; r3[1][t >> 6] = n1; r3[2][t >> 6] = n2;
  }
  __syncthreads();
  if (t == 0) {
    float nu = r3[0][0] + r3[0][1] + r3[0][2] + r3[0][3];
    float s1 = sqrtf(fmaxf(r3[1][0] + r3[1][1] + r3[1][2] + r3[1][3], 0.f));
    float s2 = sqrtf(fmaxf(r3[2][0] + r3[2][1] + r3[2][2] + r3[2][3], 0.f));
    out[pair] = nu / ((s1 + 1e-8f) * (s2 + 1e-8f));
  }
}

extern "C" void kernel_launch(void* const* d_in, const int* in_sizes, int n_in,
                              void* d_out, int out_size, void* d_ws, size_t ws_size,
                              hipStream_t stream) {
  const float* v1    = (const float*)d_in[0];
  const float* v2    = (const float*)d_in[1];
  const float* w_img = (const float*)d_in[2];
  const float* w_txt = (const float*)d_in[3];
  const float* w1a   = (const float*)d_in[4];
  const float* b1a   = (const float*)d_in[5];
  const float* w2a   = (const float*)d_in[6];
  const float* b2a   = (const float*)d_in[7];
  const float* w1b   = (const float*)d_in[8];
  const float* b1b   = (const float*)d_in[9];
  const float* w2b   = (const float*)d_in[10];
  const float* b2b   = (const float*)d_in[11];
  float* out = (float*)d_out;

  // fp32 region (k1/k2 slots unused — kept for layout stability)
  float* ws   = (float*)d_ws;
  float* k1   = ws;                           // 1728*1024 (dead)
  float* k2   = k1 + (size_t)1728 * 1024;     // 1440*1024 (dead)
  float* G2a  = k2 + (size_t)1440 * 1024;     // 1440*1024
  float* G1b  = G2a + (size_t)1440 * 1024;    // 1728*1024
  float* Sbuf = G1b + (size_t)1728 * 1024;    // 1440*1728
  float* Cbuf = Sbuf + (size_t)1440 * 1728;   // 1440*1728 (region reused for YA)
  float* g22  = Cbuf + (size_t)1440 * 1728;   // dead slot -> w2at/w2bt home
  float* g11  = g22 + (size_t)48 * 900;
  (void)k1; (void)k2;

  // split-bf16 fragment region
  unsigned short* fb    = (unsigned short*)(g11 + (size_t)48 * 1296);
  unsigned short* v1f   = fb;                                  // 108 tiles
  unsigned short* v2f   = v1f + (size_t)108 * 32768;           //  92 tiles
  unsigned short* k1f   = v2f + (size_t)92 * 32768;            // 108 tiles
  unsigned short* k2f   = k1f + (size_t)108 * 32768;           //  92 tiles
  unsigned short* wimgf = k2f + (size_t)92 * 32768;            //  64 tiles each
  unsigned short* wtxtf = wimgf + (size_t)64 * 32768;
  unsigned short* w1af  = wtxtf + (size_t)64 * 32768;
  unsigned short* w1bf  = w1af + (size_t)64 * 32768;
  unsigned short* G2aF  = w1bf + (size_t)64 * 32768;           // 48 * 65536 ush
  unsigned short* G1bF  = G2aF + (size_t)48 * 65536;           // 48 * 131072 ush

  // w2 transposed (float4 per col) lives in the DEAD g22 slot — written by
  // conv6 (first kernel), read only by pair_dir.
  float4* w2at = (float4*)g22;                // 1024 float4
  float4* w2bt = w2at + 1024;                 // 1024 float4

  // u buffers ALIAS G2a fp32 (dead after cross_convG; pair_dir runs after).
  float* U2buf = G2a;                          // 48*48*32
  float* U1buf = U2buf + (size_t)48 * 48 * 32; // 48*48*40
  // YA ALIASES Cbuf region (never written otherwise): 9.44 MB <= 9.95 MB.
  float* YA = Cbuf;
  // YB ALIASES k1f/k2f frag region (dead after cross_convG): 9.44 MB <= 13.1 MB.
  float* YB = (float*)k1f;

  conv6<<<dim3(864, 6), 256, 0, stream>>>(v1, v2, w_img, w_txt, w1a, w1b,
                                          w2a, w2b,
                                          v1f, v2f, wimgf, wtxtf, w1af, w1bf,
                                          w2at, w2bt);

  proj_fused<<<dim3(16, 14, 4), 128, 0, stream>>>(
      (const bf16x8*)v1f, (const bf16x8*)v2f, (const bf16x8*)wimgf,
      (const bf16x8*)wtxtf, (const bf16x8*)w1af, (const bf16x8*)w1bf,
      G2a, G1b, k1f, k2f);

  cross_convG<<<3396, 128, 0, stream>>>(
      (const bf16x8*)k2f, (const bf16x8*)k1f, G2a, G1b,
      Sbuf, G2aF, G1bF);

  pair_dir<<<1152, 256, 0, stream>>>(
      Sbuf, (const bf16x8*)G2aF, (const bf16x8*)G1bF,
      b1a, w2at, b2a, b1b, w2bt, b2b, U1buf, U2buf);
  y_batch<<<dim3(48, 2, 4), 256, 0, stream>>>(v1, v2, U1buf, U2buf, YA, YB);
  pair_final<<<2304, 256, 0, stream>>>(YA, YB, out);
}

// Round 15
// 276.335 us; speedup vs baseline: 1.0961x; 1.0121x over previous
//
#include <hip/hip_runtime.h>

#define D 1024
#define NB1 48
#define NB2 48
#define RR 36
#define LL 30
#define NH 4

typedef short bf16x8 __attribute__((ext_vector_type(8)));
typedef float f32x4 __attribute__((ext_vector_type(4)));
typedef float f32x2 __attribute__((ext_vector_type(2)));
typedef unsigned short u16x8 __attribute__((ext_vector_type(8)));

#define MFMA16(a, b, c) __builtin_amdgcn_mfma_f32_16x16x32_bf16(a, b, c, 0, 0, 0)

__device__ __forceinline__ unsigned short f2bf(float x) {
  unsigned u = __float_as_uint(x);
  u += 0x7FFF + ((u >> 16) & 1);
  return (unsigned short)(u >> 16);
}
__device__ __forceinline__ float bf2f(unsigned short h) {
  return __uint_as_float(((unsigned)h) << 16);
}
__device__ __forceinline__ void split8(const float* v, bf16x8& h8, bf16x8& l8) {
  u16x8 hi, lo;
#pragma unroll
  for (int i = 0; i < 8; ++i) {
    unsigned short h = f2bf(v[i]);
    hi[i] = h;
    lo[i] = f2bf(v[i] - bf2f(h));
  }
  h8 = __builtin_bit_cast(bf16x8, hi);
  l8 = __builtin_bit_cast(bf16x8, lo);
}
__device__ __forceinline__ f32x2 shflx2(f32x2 v, int m) {
  double d = __builtin_bit_cast(double, v);
  d = __shfl_xor(d, m);
  return __builtin_bit_cast(f32x2, d);
}

// ---- fp32 row-major (rows x 1024) -> split-bf16 MFMA fragment layout ----
__device__ __forceinline__ void conv_body(const float* __restrict__ X,
                                          unsigned short* __restrict__ out,
                                          int rows, int g) {
  const int lane = threadIdx.x & 63;
  const int tile = g >> 5, kc = g & 31;
  const int row = tile * 16 + (lane & 15);
  const int k = kc * 32 + (lane >> 4) * 8;
  float v[8];
  if (row < rows) {
    const float4* s = (const float4*)(X + (size_t)row * 1024 + k);
    float4 x0 = s[0], x1 = s[1];
    v[0] = x0.x; v[1] = x0.y; v[2] = x0.z; v[3] = x0.w;
    v[4] = x1.x; v[5] = x1.y; v[6] = x1.z; v[7] = x1.w;
  } else {
#pragma unroll
    for (int i = 0; i < 8; ++i) v[i] = 0.f;
  }
  bf16x8 hi, lo;
  split8(v, hi, lo);
  bf16x8* o = (bf16x8*)(out + (size_t)g * 1024 + lane * 8);
  o[0] = hi;
  o[64] = lo;
}

// 6 input matrices in one launch + w2 transpose (y==0, x<4). grid (864, 6)
__global__ __launch_bounds__(256) void conv6(
    const float* __restrict__ v1, const float* __restrict__ v2,
    const float* __restrict__ wimg, const float* __restrict__ wtxt,
    const float* __restrict__ w1a, const float* __restrict__ w1b,
    const float* __restrict__ w2a, const float* __restrict__ w2b,
    unsigned short* v1f, unsigned short* v2f, unsigned short* wimgf,
    unsigned short* wtxtf, unsigned short* w1af, unsigned short* w1bf,
    float4* __restrict__ w2at, float4* __restrict__ w2bt) {
  if (blockIdx.y == 0 && blockIdx.x < 4) {
    int col = blockIdx.x * 256 + threadIdx.x;
    w2at[col] = make_float4(w2a[col], w2a[1024 + col], w2a[2048 + col], w2a[3072 + col]);
    w2bt[col] = make_float4(w2b[col], w2b[1024 + col], w2b[2048 + col], w2b[3072 + col]);
  }
  const float* X; unsigned short* O; int rows;
  switch (blockIdx.y) {
    case 0: X = v1; O = v1f; rows = 1728; break;
    case 1: X = v2; O = v2f; rows = 1440; break;
    case 2: X = wimg; O = wimgf; rows = 1024; break;
    case 3: X = wtxt; O = wtxtf; rows = 1024; break;
    case 4: X = w1a; O = w1af; rows = 1024; break;
    default: X = w1b; O = w1bf; rows = 1024; break;
  }
  const int tiles = (rows + 15) >> 4;
  const int g = blockIdx.x * 4 + (threadIdx.x >> 6);
  if (g >= tiles * 32) return;
  conv_body(X, O, rows, g);
}

// ---- split-bf16 MFMA GEMM core: 2 waves/block, each 4x4 tiles (128x64 out) ----
#define LOAD_FRAGS(AH, AL, BH, BL)                                              \
  {                                                                             \
    _Pragma("unroll") for (int i = 0; i < 4; ++i) {                             \
      AH[i] = Af[ab[i]]; AL[i] = Af[ab[i] + 64]; ab[i] += 128;                  \
    }                                                                           \
    _Pragma("unroll") for (int j = 0; j < 4; ++j) {                             \
      BH[j] = Bf[bb[j]]; BL[j] = Bf[bb[j] + 64]; bb[j] += 128;                  \
    }                                                                           \
  }

#define MFMA_SET(AH, AL, BH, BL)                                                \
  _Pragma("unroll") for (int i = 0; i < 4; ++i)                                 \
      _Pragma("unroll") for (int j = 0; j < 4; ++j) {                           \
    acc[i][j] = MFMA16(AH[i], BH[j], acc[i][j]);                                \
    acc[i][j] = MFMA16(AL[i], BH[j], acc[i][j]);                                \
    acc[i][j] = MFMA16(AH[i], BL[j], acc[i][j]);                                \
  }

__device__ __forceinline__ void gemm2w_acc(const bf16x8* __restrict__ Af,
                                           const bf16x8* __restrict__ Bf,
                                           int Mtiles, int Ntiles,
                                           int mb, int nb, int lane,
                                           f32x4 (&acc)[4][4]) {
  int ab[4], bb[4];
#pragma unroll
  for (int i = 0; i < 4; ++i) {
    int tm = mb + i; if (tm > Mtiles - 1) tm = Mtiles - 1;
    ab[i] = tm * 4096 + lane;
    int tn = nb + i; if (tn > Ntiles - 1) tn = Ntiles - 1;
    bb[i] = tn * 4096 + lane;
  }
#pragma unroll
  for (int i = 0; i < 4; ++i)
#pragma unroll
    for (int j = 0; j < 4; ++j) acc[i][j] = (f32x4){0.f, 0.f, 0.f, 0.f};

  bf16x8 ahA[4], alA[4], bhA[4], blA[4];
  bf16x8 ahB[4], alB[4], bhB[4], blB[4];
  LOAD_FRAGS(ahA, alA, bhA, blA);
#pragma unroll 1
  for (int kc = 0; kc < 30; kc += 2) {
    LOAD_FRAGS(ahB, alB, bhB, blB);
    MFMA_SET(ahA, alA, bhA, blA);
    LOAD_FRAGS(ahA, alA, bhA, blA);
    MFMA_SET(ahB, alB, bhB, blB);
  }
  LOAD_FRAGS(ahB, alB, bhB, blB);
  MFMA_SET(ahA, alA, bhA, blA);
  MFMA_SET(ahB, alB, bhB, blB);
}

__device__ __forceinline__ void gemm2w_store_fp32(f32x4 (&acc)[4][4],
                                                  float* __restrict__ C,
                                                  int M, int N, float scale,
                                                  int mb, int nb, int lane) {
  const int c16 = lane & 15, q = lane >> 4;
#pragma unroll
  for (int i = 0; i < 4; ++i) {
#pragma unroll
    for (int reg = 0; reg < 4; ++reg) {
      int r = (mb + i) * 16 + q * 4 + reg;
      if (r < M) {
#pragma unroll
        for (int j = 0; j < 4; ++j) {
          int col = (nb + j) * 16 + c16;
          if (col < N) C[(size_t)r * N + col] = acc[i][j][reg] * scale;
        }
      }
    }
  }
}

// 4 projection GEMMs. grid (4, 16, 14) x 128 — z FASTEST: each weight matrix's
// 4MB B-frags map to only 2 XCDs (block id = z + 4x + 64y; id%8 ∈ {z, z+4}),
// so weights stay L2-resident instead of thrashing all 8 XCDs.
// z<2: output split-bf16 k-fragments DIRECTLY (LDS transpose epilogue).
// z>=2: fp32 G2a/G1b (consumed by cross_convG's convG part).
__global__ __launch_bounds__(128) void proj_fused(
    const bf16x8* __restrict__ v1f, const bf16x8* __restrict__ v2f,
    const bf16x8* __restrict__ wimgf, const bf16x8* __restrict__ wtxtf,
    const bf16x8* __restrict__ w1af, const bf16x8* __restrict__ w1bf,
    float* G2a, float* G1b,
    unsigned short* k1f, unsigned short* k2f) {
  const int z = blockIdx.x;
  const int lane = threadIdx.x & 63;
  const int w = threadIdx.x >> 6;
  const int mb = blockIdx.z * 8 + w * 4;
  const int nb = blockIdx.y * 4;
  const bf16x8* Af = (z == 0 || z == 3) ? v1f : v2f;
  const bf16x8* Bf = (z == 0) ? wimgf : (z == 1) ? wtxtf : (z == 2) ? w1af : w1bf;
  const int Mt = (z == 0 || z == 3) ? 108 : 90;
  if ((int)blockIdx.z * 8 >= Mt) return;

  __shared__ __align__(16) float tlds[2][4][16][68];

  f32x4 acc[4][4];
  gemm2w_acc(Af, Bf, Mt, 64, mb, nb, lane, acc);

  if (z <= 1) {
    unsigned short* F = z ? k2f : k1f;
    const int c16 = lane & 15, q = lane >> 4;
#pragma unroll
    for (int i = 0; i < 4; ++i)
#pragma unroll
      for (int j = 0; j < 4; ++j)
#pragma unroll
        for (int reg = 0; reg < 4; ++reg)
          tlds[w][i][q * 4 + reg][j * 16 + c16] = acc[i][j][reg];
    __builtin_amdgcn_sched_barrier(0);
    const int r16 = lane & 15, q2 = lane >> 4;
#pragma unroll
    for (int i = 0; i < 4; ++i) {
      if (mb + i < Mt) {
#pragma unroll
        for (int kcl = 0; kcl < 2; ++kcl) {
          const float* rp = &tlds[w][i][r16][kcl * 32 + q2 * 8];
          float4 x0 = *(const float4*)rp;
          float4 x1 = *(const float4*)(rp + 4);
          float v[8];
          v[0] = x0.x; v[1] = x0.y; v[2] = x0.z; v[3] = x0.w;
          v[4] = x1.x; v[5] = x1.y; v[6] = x1.z; v[7] = x1.w;
          bf16x8 hi, lo;
          split8(v, hi, lo);
          size_t g = (size_t)(mb + i) * 32 + (nb >> 1) + kcl;
          bf16x8* o = (bf16x8*)(F + g * 1024 + lane * 8);
          o[0] = hi;
          o[64] = lo;
        }
      }
    }
  } else {
    float* C = (z == 2) ? G2a : G1b;
    const int M = (z == 2) ? 1440 : 1728;
    gemm2w_store_fp32(acc, C, M, 1024, 1.f, mb, nb, lane);
  }
}

// cross_s + convG co-scheduled in ONE 128-thr launch (both depend only on
// proj_fused; cross alone is 324 blocks = 1.27/CU grid-starved). grid 3396.
// bx<324: S = k2*k1^T. bx>=324: convG wave-tasks (2 per block):
// task = plane*3072 + bb*64 + nt, identical math to the verified convG.
__global__ __launch_bounds__(128) void cross_convG(
    const bf16x8* __restrict__ k2f, const bf16x8* __restrict__ k1f,
    const float* __restrict__ G2a, const float* __restrict__ G1b,
    float* __restrict__ Sbuf,
    unsigned short* G2aF, unsigned short* G1bF) {
  const int bx = blockIdx.x;
  const int lane = threadIdx.x & 63, w = threadIdx.x >> 6;
  if (bx < 324) {
    const int x = bx % 27, y = bx / 27;
    const int mb = y * 8 + w * 4;
    const int nb = x * 4;
    f32x4 acc[4][4];
    gemm2w_acc(k2f, k1f, 90, 108, mb, nb, lane, acc);
    gemm2w_store_fp32(acc, Sbuf, 1440, 1728, 0.03125f, mb, nb, lane);
    return;
  }
  const int tid = (bx - 324) * 2 + w;      // [0, 6144)
  const int plane = tid / 3072;
  const int rem = tid - plane * 3072;
  const int bb = rem >> 6, nt = rem & 63;
  const int c = lane & 15, q = lane >> 4;
  if (plane == 0) {
    float v[8];
#pragma unroll
    for (int j = 0; j < 8; ++j) {
      int l = q * 8 + j;
      v[j] = (l < LL) ? G2a[(size_t)(bb * LL + l) * D + nt * 16 + c] : 0.f;
    }
    bf16x8 hi, lo;
    split8(v, hi, lo);
    bf16x8* o = (bf16x8*)(G2aF + ((size_t)(bb * 64 + nt) * 2) * 512 + lane * 8);
    o[0] = hi;
    o[64] = lo;
  } else {
#pragma unroll
    for (int kc = 0; kc < 2; ++kc) {
      float v[8];
#pragma unroll
      for (int j = 0; j < 8; ++j) {
        int r = kc * 32 + q * 8 + j;
        v[j] = (r < RR) ? G1b[(size_t)(bb * RR + r) * D + nt * 16 + c] : 0.f;
      }
      bf16x8 hi, lo;
      split8(v, hi, lo);
      bf16x8* o = (bf16x8*)(G1bF + (((size_t)(bb * 64 + nt) * 2 + kc) * 2) * 512 + lane * 8);
      o[0] = hi;
      o[64] = lo;
    }
  }
}

// -------- wave-per-(pair,dir) kernel: grid 1152 x 256; zero __syncthreads ----
// Block composition: all 4 waves SAME dir + SAME B-matrix; XCD pinning via bx%8
// (R8-verified: FETCH 85->23MB). LDS 24KB (R11-verified): clamped A-rows,
// register-built K-pad. Hot loops unroll 8 (R14: 2->4 gave -2.6us; deepen).
__global__ __launch_bounds__(256, 4) void pair_dir(
    const float* __restrict__ Sb,
    const bf16x8* __restrict__ G2aF, const bf16x8* __restrict__ G1bF,
    const float* __restrict__ b1a, const float4* __restrict__ w2at, const float* __restrict__ b2a,
    const float* __restrict__ b1b, const float4* __restrict__ w2bt, const float* __restrict__ b2b,
    float* __restrict__ U1buf, float* __restrict__ U2buf) {
  const int t = threadIdx.x, lane = t & 63, w = t >> 6;
  const int bx = blockIdx.x;
  int a, b, dir;
  if (bx < 576) {
    dir = 0;
    const int lo = bx & 7, i = bx >> 3;
    b = lo + 8 * (i % 6);
    a = (i / 6) * 4 + w;
  } else {
    dir = 1;
    const int bx2 = bx - 576;
    const int lo = bx2 & 7, i = bx2 >> 3;
    a = lo + 8 * (i % 6);
    b = (i / 6) * 4 + w;
  }
  const int c16 = lane & 15, q = lane >> 4;

  union WSM {
    struct { float p2s[36][36]; float sa[36][NH]; float qa[36]; } A;   // 5904 B
    struct { float p1s[30][36]; float sbm[30][NH]; float qb[30]; } B;  // 4920 B
  };
  __shared__ __align__(16) WSM sm[4];
  WSM& S = sm[w];

  const float* Sab = Sb + (size_t)(b * LL) * 1728 + a * RR;

  if (dir == 0) {
    // ================= direction A (one wave) =================
    if (lane < RR) { S.A.p2s[lane][30] = 0.f; S.A.p2s[lane][31] = 0.f; }
    __builtin_amdgcn_sched_barrier(0);
    for (int i = lane; i < LL * RR; i += 64) {
      int l = i / RR, r = i - l * RR;
      S.A.p2s[r][l] = Sab[(size_t)l * 1728 + r];
    }
    __builtin_amdgcn_sched_barrier(0);
    if (lane < RR) {
      const int r = lane;
      float m = -1e30f;
      for (int l = 0; l < LL; ++l) m = fmaxf(m, S.A.p2s[r][l]);
      float s = 0.f;
      for (int l = 0; l < LL; ++l) {
        float e = __expf(S.A.p2s[r][l] - m);
        S.A.p2s[r][l] = e;
        s += e;
      }
      float inv = 1.f / s;
      for (int l = 0; l < LL; ++l) S.A.p2s[r][l] *= inv;
    }
    __builtin_amdgcn_sched_barrier(0);

    bf16x8 pAh[3], pAl[3];
#pragma unroll
    for (int mt = 0; mt < 3; ++mt) {
      int rr = mt * 16 + c16;
      if (rr > RR - 1) rr = RR - 1;      // clamped: feeds discarded score rows
      float v[8];
      const float* rp = &S.A.p2s[rr][q * 8];
      float4 x0 = *(const float4*)rp;
      float4 x1 = *(const float4*)(rp + 4);
      v[0] = x0.x; v[1] = x0.y; v[2] = x0.z; v[3] = x0.w;
      v[4] = x1.x; v[5] = x1.y; v[6] = x1.z; v[7] = x1.w;
      split8(v, pAh[mt], pAl[mt]);
    }

    f32x2 sc01[3][4], sc23[3][4];
#pragma unroll
    for (int mt = 0; mt < 3; ++mt)
#pragma unroll
      for (int reg = 0; reg < 4; ++reg) {
        sc01[mt][reg] = (f32x2){0.f, 0.f};
        sc23[mt][reg] = (f32x2){0.f, 0.f};
      }

    const bf16x8* gA = G2aF + (size_t)(b * 64) * 128 + lane;
#pragma unroll 8
    for (int it = 0; it < 64; ++it) {
      const bf16x8* gp = gA + (size_t)it * 128;
      bf16x8 Bh = gp[0], Bl = gp[64];
      const int col = it * 16 + c16;
      float4 wv = w2at[col];
      float bias = b1a[col];
      f32x2 w01 = {wv.x, wv.y}, w23 = {wv.z, wv.w};
#pragma unroll
      for (int mt = 0; mt < 3; ++mt) {
        f32x4 acc = {bias, bias, bias, bias};
        __builtin_amdgcn_s_setprio(1);
        acc = MFMA16(pAh[mt], Bh, acc);
        acc = MFMA16(pAl[mt], Bh, acc);
        acc = MFMA16(pAh[mt], Bl, acc);
        __builtin_amdgcn_s_setprio(0);
#pragma unroll
        for (int reg = 0; reg < 4; ++reg) {
          float hv = fmaxf(acc[reg], 0.f);
          f32x2 hv2 = {hv, hv};
          sc01[mt][reg] += hv2 * w01;
          sc23[mt][reg] += hv2 * w23;
        }
      }
    }
    f32x2 b01 = {b2a[0], b2a[1]}, b23 = {b2a[2], b2a[3]};
#pragma unroll
    for (int mt = 0; mt < 3; ++mt)
#pragma unroll
      for (int reg = 0; reg < 4; ++reg) {
        f32x2 v01 = sc01[mt][reg], v23 = sc23[mt][reg];
#pragma unroll
        for (int m = 1; m <= 8; m <<= 1) {
          v01 += shflx2(v01, m);
          v23 += shflx2(v23, m);
        }
        int row = mt * 16 + q * 4 + reg;
        if (c16 == 0 && row < RR) {
          f32x2* rp = (f32x2*)&S.A.sa[row][0];
          rp[0] = v01 + b01;
          rp[1] = v23 + b23;
        }
      }
    __builtin_amdgcn_sched_barrier(0);
    // head softmax over 36 rows, 16 lanes/head; then qa via cross-head shuffles
    {
      const int h = q, i = c16;
      float x0 = S.A.sa[i][h];
      float x1 = S.A.sa[i + 16][h];
      float x2 = (i < 4) ? S.A.sa[i + 32][h] : -1e30f;
      float m = fmaxf(fmaxf(x0, x1), x2);
      m = fmaxf(m, __shfl_xor(m, 1));
      m = fmaxf(m, __shfl_xor(m, 2));
      m = fmaxf(m, __shfl_xor(m, 4));
      m = fmaxf(m, __shfl_xor(m, 8));
      float e0 = __expf(x0 - m), e1 = __expf(x1 - m);
      float e2 = (i < 4) ? __expf(x2 - m) : 0.f;
      float s = e0 + e1 + e2;
      s += __shfl_xor(s, 1);
      s += __shfl_xor(s, 2);
      s += __shfl_xor(s, 4);
      s += __shfl_xor(s, 8);
      float inv = 0.25f / s;
      float p0 = e0 * inv, p1 = e1 * inv, p2v = e2 * inv;
      p0 += __shfl_xor(p0, 16); p0 += __shfl_xor(p0, 32);
      p1 += __shfl_xor(p1, 16); p1 += __shfl_xor(p1, 32);
      p2v += __shfl_xor(p2v, 16); p2v += __shfl_xor(p2v, 32);
      if (q == 0) {
        S.A.qa[i] = p0;
        S.A.qa[i + 16] = p1;
        if (i < 4) S.A.qa[i + 32] = p2v;
      }
    }
    __builtin_amdgcn_sched_barrier(0);
    // u2[l] = sum_r qa[r] * p2[r][l]
    if (lane < LL) {
      const int l = lane;
      float x = 0.f;
      for (int r = 0; r < RR; ++r) x = fmaf(S.A.qa[r], S.A.p2s[r][l], x);
      U2buf[((size_t)b * 48 + a) * 32 + l] = x;
    }
  } else {
    // ================= direction B (one wave) =================
    for (int i = lane; i < LL * RR; i += 64) {
      int l = i / RR, r = i - l * RR;
      S.B.p1s[l][r] = Sab[(size_t)l * 1728 + r];
    }
    __builtin_amdgcn_sched_barrier(0);
    if (lane < LL) {
      const int l = lane;
      float m = -1e30f;
      for (int r = 0; r < RR; ++r) m = fmaxf(m, S.B.p1s[l][r]);
      float s = 0.f;
      for (int r = 0; r < RR; ++r) {
        float e = __expf(S.B.p1s[l][r] - m);
        S.B.p1s[l][r] = e;
        s += e;
      }
      float inv = 1.f / s;
      for (int r = 0; r < RR; ++r) S.B.p1s[l][r] *= inv;
    }
    __builtin_amdgcn_sched_barrier(0);

    bf16x8 pBh[2][2], pBl[2][2];
#pragma unroll
    for (int mt = 0; mt < 2; ++mt) {
      int rr = mt * 16 + c16;
      if (rr > LL - 1) rr = LL - 1;      // clamped: feeds discarded score rows
      {
        float v[8];
        const float* rp = &S.B.p1s[rr][q * 8];
        float4 x0 = *(const float4*)rp;
        float4 x1 = *(const float4*)(rp + 4);
        v[0] = x0.x; v[1] = x0.y; v[2] = x0.z; v[3] = x0.w;
        v[4] = x1.x; v[5] = x1.y; v[6] = x1.z; v[7] = x1.w;
        split8(v, pBh[mt][0], pBl[mt][0]);
      }
      {
        float v[8];
#pragma unroll
        for (int j = 0; j < 8; ++j) {
          int r = 32 + q * 8 + j;
          v[j] = (r < RR) ? S.B.p1s[rr][r] : 0.f;
        }
        split8(v, pBh[mt][1], pBl[mt][1]);
      }
    }

    f32x2 sc01[2][4], sc23[2][4];
#pragma unroll
    for (int mt = 0; mt < 2; ++mt)
#pragma unroll
      for (int reg = 0; reg < 4; ++reg) {
        sc01[mt][reg] = (f32x2){0.f, 0.f};
        sc23[mt][reg] = (f32x2){0.f, 0.f};
      }

    const bf16x8* gB = G1bF + (size_t)(a * 64) * 256 + lane;
#pragma unroll 8
    for (int it = 0; it < 64; ++it) {
      const bf16x8* gp = gB + (size_t)it * 256;
      bf16x8 B0h = gp[0], B0l = gp[64], B1h = gp[128], B1l = gp[192];
      const int col = it * 16 + c16;
      float4 wv = w2bt[col];
      float bias = b1b[col];
      f32x2 w01 = {wv.x, wv.y}, w23 = {wv.z, wv.w};
#pragma unroll
      for (int mt = 0; mt < 2; ++mt) {
        f32x4 acc = {bias, bias, bias, bias};
        __builtin_amdgcn_s_setprio(1);
        acc = MFMA16(pBh[mt][0], B0h, acc);
        acc = MFMA16(pBl[mt][0], B0h, acc);
        acc = MFMA16(pBh[mt][0], B0l, acc);
        acc = MFMA16(pBh[mt][1], B1h, acc);
        acc = MFMA16(pBl[mt][1], B1h, acc);
        acc = MFMA16(pBh[mt][1], B1l, acc);
        __builtin_amdgcn_s_setprio(0);
#pragma unroll
        for (int reg = 0; reg < 4; ++reg) {
          float hv = fmaxf(acc[reg], 0.f);
          f32x2 hv2 = {hv, hv};
          sc01[mt][reg] += hv2 * w01;
          sc23[mt][reg] += hv2 * w23;
        }
      }
    }
    f32x2 b01 = {b2b[0], b2b[1]}, b23 = {b2b[2], b2b[3]};
#pragma unroll
    for (int mt = 0; mt < 2; ++mt)
#pragma unroll
      for (int reg = 0; reg < 4; ++reg) {
        f32x2 v01 = sc01[mt][reg], v23 = sc23[mt][reg];
#pragma unroll
        for (int m = 1; m <= 8; m <<= 1) {
          v01 += shflx2(v01, m);
          v23 += shflx2(v23, m);
        }
        int row = mt * 16 + q * 4 + reg;
        if (c16 == 0 && row < LL) {
          f32x2* rp = (f32x2*)&S.B.sbm[row][0];
          rp[0] = v01 + b01;
          rp[1] = v23 + b23;
        }
      }
    __builtin_amdgcn_sched_barrier(0);
    // head softmax over 30 rows; qb via cross-head shuffles
    {
      const int h = q, i = c16;
      float x0 = S.B.sbm[i][h];
      float x1 = (i < 14) ? S.B.sbm[i + 16][h] : -1e30f;
      float m = fmaxf(x0, x1);
      m = fmaxf(m, __shfl_xor(m, 1));
      m = fmaxf(m, __shfl_xor(m, 2));
      m = fmaxf(m, __shfl_xor(m, 4));
      m = fmaxf(m, __shfl_xor(m, 8));
      float e0 = __expf(x0 - m);
      float e1 = (i < 14) ? __expf(x1 - m) : 0.f;
      float s = e0 + e1;
      s += __shfl_xor(s, 1);
      s += __shfl_xor(s, 2);
      s += __shfl_xor(s, 4);
      s += __shfl_xor(s, 8);
      float inv = 0.25f / s;
      float p0 = e0 * inv, p1 = e1 * inv;
      p0 += __shfl_xor(p0, 16); p0 += __shfl_xor(p0, 32);
      p1 += __shfl_xor(p1, 16); p1 += __shfl_xor(p1, 32);
      if (q == 0) {
        S.B.qb[i] = p0;
        if (i < 14) S.B.qb[i + 16] = p1;
      }
    }
    __builtin_amdgcn_sched_barrier(0);
    // u1[r] = sum_l qb[l] * p1[l][r]
    if (lane < RR) {
      const int r = lane;
      float x = 0.f;
      for (int l = 0; l < LL; ++l) x = fmaf(S.B.qb[l], S.B.p1s[l][r], x);
      U1buf[((size_t)a * 48 + b) * 40 + r] = x;
    }
  }
}

// Y_A[b] = U2_b(48x30) * V2_b(30x1024) ; Y_B[a] = U1_a(48x36) * V1_a(36x1024)
// grid (48, 2, 4) x 256. Each thread owns one col, 48 accumulators.
__global__ __launch_bounds__(256) void y_batch(
    const float* __restrict__ v1, const float* __restrict__ v2,
    const float* __restrict__ U1buf, const float* __restrict__ U2buf,
    float* __restrict__ YA, float* __restrict__ YB) {
  const int bb = blockIdx.x;
  const int col = blockIdx.z * 256 + threadIdx.x;
  __shared__ float us[48 * 40];
  float y[48];
#pragma unroll
  for (int i = 0; i < 48; ++i) y[i] = 0.f;
  if (blockIdx.y == 0) {
    for (int i = threadIdx.x; i < 48 * 32; i += 256) us[i] = U2buf[(size_t)bb * 1536 + i];
    __syncthreads();
    const float* V = v2 + (size_t)bb * LL * 1024 + col;
    for (int l = 0; l < LL; ++l) {
      float v = V[(size_t)l * 1024];
#pragma unroll
      for (int i = 0; i < 48; ++i) y[i] = fmaf(us[i * 32 + l], v, y[i]);
    }
    float* Yo = YA + (size_t)bb * 48 * 1024 + col;
#pragma unroll
    for (int i = 0; i < 48; ++i) Yo[(size_t)i * 1024] = y[i];
  } else {
    for (int i = threadIdx.x; i < 48 * 40; i += 256) us[i] = U1buf[(size_t)bb * 1920 + i];
    __syncthreads();
    const float* V = v1 + (size_t)bb * RR * 1024 + col;
    for (int r = 0; r < RR; ++r) {
      float v = V[(size_t)r * 1024];
#pragma unroll
      for (int i = 0; i < 48; ++i) y[i] = fmaf(us[i * 40 + r], v, y[i]);
    }
    float* Yo = YB + (size_t)bb * 48 * 1024 + col;
#pragma unroll
    for (int i = 0; i < 48; ++i) Yo[(size_t)i * 1024] = y[i];
  }
}

// out = (y_A . y_B) / ((sqrt(|y_A|^2)+eps)(sqrt(|y_B|^2)+eps)). grid 2304 x 256
__global__ __launch_bounds__(256) void pair_final(
    const float* __restrict__ YA, const float* __restrict__ YB,
    float* __restrict__ out) {
  const int pair = blockIdx.x;
  const int a = pair / NB2;
  const int b = pair - a * NB2;
  const int t = threadIdx.x;
  const float4* ya = (const float4*)(YA + ((size_t)b * 48 + a) * 1024);
  const float4* yb = (const float4*)(YB + ((size_t)a * 48 + b) * 1024);
  float4 va = ya[t], vb = yb[t];
  float num = va.x * vb.x + va.y * vb.y + va.z * vb.z + va.w * vb.w;
  float n1 = va.x * va.x + va.y * va.y + va.z * va.z + va.w * va.w;
  float n2 = vb.x * vb.x + vb.y * vb.y + vb.z * vb.z + vb.w * vb.w;
#pragma unroll
  for (int off = 32; off; off >>= 1) {
    num += __shfl_down(num, off);
    n1 += __shfl_down(n1, off);
    n2 += __shfl_down(n2, off);
  }
  __shared__ float r3[3][4];
  if ((t & 63) == 0) {
    r3[0][t >> 6] = num; r3[1][t >> 6] = n1; r3[2][t >> 6] = n2;
  }
  __syncthreads();
  if (t == 0) {
    float nu = r3[0][0] + r3[0][1] + r3[0][2] + r3[0][3];
    float s1 = sqrtf(fmaxf(r3[1][0] + r3[1][1] + r3[1][2] + r3[1][3], 0.f));
    float s2 = sqrtf(fmaxf(r3[2][0] + r3[2][1] + r3[2][2] + r3[2][3], 0.f));
    out[pair] = nu / ((s1 + 1e-8f) * (s2 + 1e-8f));
  }
}

extern "C" void kernel_launch(void* const* d_in, const int* in_sizes, int n_in,
                              void* d_out, int out_size, void* d_ws, size_t ws_size,
                              hipStream_t stream) {
  const float* v1    = (const float*)d_in[0];
  const float* v2    = (const float*)d_in[1];
  const float* w_img = (const float*)d_in[2];
  const float* w_txt = (const float*)d_in[3];
  const float* w1a   = (const float*)d_in[4];
  const float* b1a   = (const float*)d_in[5];
  const float* w2a   = (const float*)d_in[6];
  const float* b2a   = (const float*)d_in[7];
  const float* w1b   = (const float*)d_in[8];
  const float* b1b   = (const float*)d_in[9];
  const float* w2b   = (const float*)d_in[10];
  const float* b2b   = (const float*)d_in[11];
  float* out = (float*)d_out;

  // fp32 region (k1/k2 slots unused — kept for layout stability)
  float* ws   = (float*)d_ws;
  float* k1   = ws;                           // 1728*1024 (dead)
  float* k2   = k1 + (size_t)1728 * 1024;     // 1440*1024 (dead)
  float* G2a  = k2 + (size_t)1440 * 1024;     // 1440*1024
  float* G1b  = G2a + (size_t)1440 * 1024;    // 1728*1024
  float* Sbuf = G1b + (size_t)1728 * 1024;    // 1440*1728
  float* Cbuf = Sbuf + (size_t)1440 * 1728;   // 1440*1728 (region reused for YA)
  float* g22  = Cbuf + (size_t)1440 * 1728;   // dead slot -> w2at/w2bt home
  float* g11  = g22 + (size_t)48 * 900;
  (void)k1; (void)k2;

  // split-bf16 fragment region
  unsigned short* fb    = (unsigned short*)(g11 + (size_t)48 * 1296);
  unsigned short* v1f   = fb;                                  // 108 tiles
  unsigned short* v2f   = v1f + (size_t)108 * 32768;           //  92 tiles
  unsigned short* k1f   = v2f + (size_t)92 * 32768;            // 108 tiles
  unsigned short* k2f   = k1f + (size_t)108 * 32768;           //  92 tiles
  unsigned short* wimgf = k2f + (size_t)92 * 32768;            //  64 tiles each
  unsigned short* wtxtf = wimgf + (size_t)64 * 32768;
  unsigned short* w1af  = wtxtf + (size_t)64 * 32768;
  unsigned short* w1bf  = w1af + (size_t)64 * 32768;
  unsigned short* G2aF  = w1bf + (size_t)64 * 32768;           // 48 * 65536 ush
  unsigned short* G1bF  = G2aF + (size_t)48 * 65536;           // 48 * 131072 ush

  // w2 transposed (float4 per col) lives in the DEAD g22 slot — written by
  // conv6 (first kernel), read only by pair_dir.
  float4* w2at = (float4*)g22;                // 1024 float4
  float4* w2bt = w2at + 1024;                 // 1024 float4

  // u buffers ALIAS G2a fp32 (dead after cross_convG; pair_dir runs after).
  float* U2buf = G2a;                          // 48*48*32
  float* U1buf = U2buf + (size_t)48 * 48 * 32; // 48*48*40
  // YA ALIASES Cbuf region (never written otherwise): 9.44 MB <= 9.95 MB.
  float* YA = Cbuf;
  // YB ALIASES k1f/k2f frag region (dead after cross_convG): 9.44 MB <= 13.1 MB.
  float* YB = (float*)k1f;

  conv6<<<dim3(864, 6), 256, 0, stream>>>(v1, v2, w_img, w_txt, w1a, w1b,
                                          w2a, w2b,
                                          v1f, v2f, wimgf, wtxtf, w1af, w1bf,
                                          w2at, w2bt);

  proj_fused<<<dim3(4, 16, 14), 128, 0, stream>>>(
      (const bf16x8*)v1f, (const bf16x8*)v2f, (const bf16x8*)wimgf,
      (const bf16x8*)wtxtf, (const bf16x8*)w1af, (const bf16x8*)w1bf,
      G2a, G1b, k1f, k2f);

  cross_convG<<<3396, 128, 0, stream>>>(
      (const bf16x8*)k2f, (const bf16x8*)k1f, G2a, G1b,
      Sbuf, G2aF, G1bF);

  pair_dir<<<1152, 256, 0, stream>>>(
      Sbuf, (const bf16x8*)G2aF, (const bf16x8*)G1bF,
      b1a, w2at, b2a, b1b, w2bt, b2b, U1buf, U2buf);
  y_batch<<<dim3(48, 2, 4), 256, 0, stream>>>(v1, v2, U1buf, U2buf, YA, YB);
  pair_final<<<2304, 256, 0, stream>>>(YA, YB, out);
}